// Round 2
// baseline (264.990 us; speedup 1.0000x reference)
//
#include <hip/hip_runtime.h>
#include <hip/hip_bf16.h>
#include <hip/hip_fp16.h>

#define NNODES 50000
#define NEG_SLOPE 0.2f
#define BKT_SHIFT 8
#define NBKT ((NNODES + 255) >> 8)   // 196 buckets of 256 dsts
#define STRIDE 5120                   // fixed slots per bucket (avg 4082, +16 sigma)
#define PCHUNK 2048                   // partition chunk (256 thr x 8 edges)
#define PEPT 8

typedef _Float16 half8 __attribute__((ext_vector_type(8)));
typedef float v4f __attribute__((ext_vector_type(4)));

__device__ __forceinline__ int rfl(int v) { return __builtin_amdgcn_readfirstlane(v); }

// pack W[K][C] fp32 into MFMA B-fragment order
__device__ __forceinline__ void pack_one(const float* W, _Float16* Wp, int K, int C, int tid) {
    int KC = K / 32;
    int l = tid & 63;
    int kc = (tid >> 6) % KC;
    int t = tid / (KC * 64);
    int cc = l & 15, q = l >> 4;
    half8 b;
#pragma unroll
    for (int j = 0; j < 8; j++)
        b[j] = (_Float16)W[(size_t)(kc * 32 + q * 8 + j) * C + t * 16 + cc];
    *(half8*)(Wp + (size_t)tid * 8) = b;
}

// ---------------- Kernel AB: gemm0 + Wp2 pack + edge partition, ONE launch ----------
__global__ __launch_bounds__(256) void kernelAB(
    const float* __restrict__ x, const float* __restrict__ W0,
    const float* __restrict__ AL, const float* __restrict__ AR,
    _Float16* __restrict__ featA, float2* __restrict__ el2A, float2* __restrict__ er2A,
    const float* __restrict__ W2, _Float16* __restrict__ Wp2,
    const int* __restrict__ src, const int* __restrict__ dst,
    int* __restrict__ bcursor, int2* __restrict__ ebuf, int E, int N) {
    int blk = blockIdx.x;
    if (blk >= 786) {
        // ---- partition branch ----
        __shared__ int hist[NBKT];
        __shared__ int gbase[NBKT];
        int t = threadIdx.x;
        for (int i = t; i < NBKT; i += 256) hist[i] = 0;
        __syncthreads();
        int base = (blk - 786) * PCHUNK;
        int sreg[PEPT], dreg[PEPT], rreg[PEPT], breg[PEPT];
#pragma unroll
        for (int k = 0; k < PEPT; k++) {
            int i = base + k * 256 + t;
            if (i < E) {
                sreg[k] = src[i];
                dreg[k] = dst[i];
                breg[k] = dreg[k] >> BKT_SHIFT;
                rreg[k] = atomicAdd(&hist[breg[k]], 1);
            } else {
                breg[k] = -1;
            }
        }
        __syncthreads();
        for (int i = t; i < NBKT; i += 256)
            if (hist[i]) gbase[i] = i * STRIDE + atomicAdd(&bcursor[i * 16], hist[i]);
        __syncthreads();
#pragma unroll
        for (int k = 0; k < PEPT; k++) {
            if (breg[k] >= 0)
                ebuf[(size_t)(gbase[breg[k]] + rreg[k])] = make_int2(sreg[k], dreg[k]);
        }
        return;
    }
    if (blk >= 782) {
        int tid = (blk - 782) * 256 + threadIdx.x;
        if (tid < 8 * 2 * 64) pack_one(W2, Wp2, 64, 128, tid);
        return;
    }
    // ---- gemm0 branch ----
    int wave = threadIdx.x >> 6, lane = threadIdx.x & 63;
    int mtile = blk * 4 + wave;
    if (mtile * 16 >= N) return;
    int m0 = mtile * 16;
    int c = lane & 15, q = lane >> 4;
    v4f acc[4];
#pragma unroll
    for (int t = 0; t < 4; t++) acc[t] = (v4f){0.f, 0.f, 0.f, 0.f};
    const size_t arow = (size_t)(m0 + c) * 128 + q * 8;
#pragma unroll
    for (int kc = 0; kc < 4; kc++) {
        const float* xr = x + arow + kc * 32;
        float4 f0 = *(const float4*)xr;
        float4 f1 = *(const float4*)(xr + 4);
        float fv[8] = {f0.x, f0.y, f0.z, f0.w, f1.x, f1.y, f1.z, f1.w};
        half8 ah, av;
#pragma unroll
        for (int j = 0; j < 8; j++) {
            ah[j] = (_Float16)fv[j];
            av[j] = (_Float16)(fv[j] - (float)ah[j]);
        }
#pragma unroll
        for (int tt = 0; tt < 4; tt++) {
            half8 b;
#pragma unroll
            for (int j = 0; j < 8; j++)
                b[j] = (_Float16)W0[(size_t)(kc * 32 + q * 8 + j) * 64 + tt * 16 + c];
            acc[tt] = __builtin_amdgcn_mfma_f32_16x16x32_f16(ah, b, acc[tt], 0, 0, 0);
            acc[tt] = __builtin_amdgcn_mfma_f32_16x16x32_f16(av, b, acc[tt], 0, 0, 0);
        }
    }
#pragma unroll
    for (int tt = 0; tt < 4; tt++)
#pragma unroll
        for (int r = 0; r < 4; r++) {
            int row = m0 + q * 4 + r;
            featA[(size_t)row * 64 + tt * 16 + c] = (_Float16)acc[tt][r];
        }
    float alv[4], arv[4];
#pragma unroll
    for (int tt = 0; tt < 4; tt++) { alv[tt] = AL[tt * 16 + c]; arv[tt] = AR[tt * 16 + c]; }
#pragma unroll
    for (int r = 0; r < 4; r++) {
        float l0 = 0.f, l1 = 0.f, r0 = 0.f, r1 = 0.f;
#pragma unroll
        for (int tt = 0; tt < 4; tt++) {
            float v = acc[tt][r];
            if (tt < 2) { l0 = fmaf(v, alv[tt], l0); r0 = fmaf(v, arv[tt], r0); }
            else        { l1 = fmaf(v, alv[tt], l1); r1 = fmaf(v, arv[tt], r1); }
        }
#pragma unroll
        for (int m = 1; m < 16; m <<= 1) {
            l0 += __shfl_xor(l0, m, 64);
            l1 += __shfl_xor(l1, m, 64);
            r0 += __shfl_xor(r0, m, 64);
            r1 += __shfl_xor(r1, m, 64);
        }
        if (c == 0) {
            int row = m0 + q * 4 + r;
            el2A[row] = make_float2(l0, l1);
            er2A[row] = make_float2(r0, r1);
        }
    }
}

// ---------------- local sort: 1024 threads/bucket (4x parallel vs 256) ----
__global__ __launch_bounds__(1024) void local_sort(const int2* __restrict__ ebuf,
                                                   const int* __restrict__ bcursor,
                                                   int2* __restrict__ rowse,
                                                   int* __restrict__ csrc, int N) {
    __shared__ int lcnt[256], lrow[256], ws[4];
    int b = blockIdx.x;
    int d0 = b << BKT_SHIFT;
    int t = threadIdx.x;
    int base = b * STRIDE;
    int endE = base + bcursor[b * 16];
    if (t < 256) lcnt[t] = 0;
    __syncthreads();
    for (int i = base + t; i < endE; i += 1024)
        atomicAdd(&lcnt[ebuf[i].y - d0], 1);
    __syncthreads();
    int v = (t < 256) ? lcnt[t] : 0;
    int lane = t & 63;
    int x = v;
#pragma unroll
    for (int m = 1; m < 64; m <<= 1) {
        int y = __shfl_up(x, m, 64);
        if (lane >= m) x += y;
    }
    if (t < 256 && lane == 63) ws[t >> 6] = x;
    __syncthreads();
    if (t < 256) {
        int w = t >> 6, waveoff = 0;
#pragma unroll
        for (int k = 0; k < 4; k++) if (k < w) waveoff += ws[k];
        int excl = base + waveoff + x - v;
        lrow[t] = excl;
        int d = d0 + t;
        if (d < N) rowse[d] = make_int2(excl, excl + v);
        lcnt[t] = 0;
    }
    __syncthreads();
    for (int i = base + t; i < endE; i += 1024) {
        int2 e = ebuf[i];
        int ld = e.y - d0;
        int p = lrow[ld] + atomicAdd(&lcnt[ld], 1);
        csrc[p] = e.x;
    }
}

// ---------------- agg0 + fused fp32 matvec gemm1 (64->64) + layer-1 logits ----
// 16-wide gather groups: one full latency exposure per average-degree node.
// s-summation keeps the original pairwise-8 order (bit-identical).
__global__ __launch_bounds__(256) void agg0_gemm1(
    const int2* __restrict__ rowse, const int* __restrict__ csrc,
    const float2* __restrict__ el2A, const float2* __restrict__ er2A,
    const _Float16* __restrict__ featA, const float* __restrict__ b0,
    const float* __restrict__ W1, const float* __restrict__ al1, const float* __restrict__ ar1,
    _Float16* __restrict__ featB, float2* __restrict__ el2B, float2* __restrict__ er2B,
    int N) {
    __shared__ int2 stA[4][64], stB[4][64];
    __shared__ float vbuf[4][64];
    __shared__ float4 w1v[16 * 64];   // [k4][lane] -> (W1[4k4+0..3][lane])
    int wave = threadIdx.x >> 6, lane = threadIdx.x & 63, h = lane >> 5;
    for (int i = threadIdx.x; i < 64 * 64; i += 256) {
        int k = i >> 6, cc = i & 63;
        ((float*)w1v)[((((k >> 2) << 6) + cc) << 2) | (k & 3)] = W1[i];
    }
    __syncthreads();
    float bl = b0[lane];
    float al1v = al1[lane], ar1v = ar1[lane];
    const int2* stH = h ? stB[wave] : stA[wave];
    for (int n0 = blockIdx.x * 4 + wave; n0 < N; n0 += gridDim.x * 4) {
        int n = rfl(n0);
        int2 se = rowse[n];
        int beg = rfl(se.x), end = rfl(se.y);
        float2 rr = er2A[n];
        float s = 0.f, acc = 0.f;
        for (int base = beg; base < end; base += 64) {
            int idx = base + lane;
            int sv = 0; float wxv = 0.f, wyv = 0.f;
            if (idx < end) {
                sv = csrc[idx];
                float2 l = el2A[sv];
                float t0 = l.x + rr.x; t0 = t0 > 0.f ? t0 : NEG_SLOPE * t0;
                float t1 = l.y + rr.y; t1 = t1 > 0.f ? t1 : NEG_SLOPE * t1;
                wxv = __expf(t0); wyv = __expf(t1);
            }
            stA[wave][lane] = make_int2(sv, __float_as_int(wxv));
            stB[wave][lane] = make_int2(sv, __float_as_int(wyv));
            int cnt = (min(64, end - base) + 15) & ~15;   // padded: no scalar tail
            for (int j = 0; j < cnt; j += 16) {
                float f[16], w[16];
#pragma unroll
                for (int u = 0; u < 16; u += 2) {
                    int4 e = *(const int4*)(stH + j + u);
                    w[u]     = __int_as_float(e.y);
                    w[u + 1] = __int_as_float(e.w);
                    f[u]     = (float)featA[(size_t)e.x * 64 + lane];
                    f[u + 1] = (float)featA[(size_t)e.z * 64 + lane];
                }
                s += ((w[0] + w[1]) + (w[2] + w[3])) + ((w[4] + w[5]) + (w[6] + w[7]));
                s += ((w[8] + w[9]) + (w[10] + w[11])) + ((w[12] + w[13]) + (w[14] + w[15]));
#pragma unroll
                for (int u = 0; u < 16; u++) acc = fmaf(w[u], f[u], acc);
            }
        }
        float v = (s > 0.f) ? acc / s : 0.f;
        v = fmaxf(v + bl, 0.f);
        vbuf[wave][lane] = v;
        const float4* vv = (const float4*)vbuf[wave];
        float f = 0.f;
#pragma unroll
        for (int kk = 0; kk < 16; kk++) {
            float4 v4 = vv[kk];                 // LDS broadcast (same addr all lanes)
            float4 w4 = w1v[(kk << 6) + lane];  // contiguous b128, conflict-free
            f = fmaf(v4.x, w4.x, f);
            f = fmaf(v4.y, w4.y, f);
            f = fmaf(v4.z, w4.z, f);
            f = fmaf(v4.w, w4.w, f);
        }
        featB[(size_t)n * 64 + lane] = (_Float16)f;
        float vl = f * al1v, vr = f * ar1v;
#pragma unroll
        for (int m = 1; m < 32; m <<= 1) {
            vl += __shfl_xor(vl, m, 64);
            vr += __shfl_xor(vr, m, 64);
        }
        if ((lane & 31) == 0) {
            ((float*)el2B)[n * 2 + h] = vl;
            ((float*)er2B)[n * 2 + h] = vr;
        }
    }
}

// ---------------- FUSED agg1 + gemm2: each wave aggregates its own 16 nodes ----
// into a transposed LDS tile vt[feat][node] (stride 17 words: 2-way banks, free),
// then does its own 16-row MFMA tile (64->128, hi/lo split from fp32 in LDS).
// No ahi/alo HBM round-trip, no cross-wave sync needed (all wave-local).
__global__ __launch_bounds__(256) void agg1_gemm2(
    const int2* __restrict__ rowse, const int* __restrict__ csrc,
    const float2* __restrict__ el2, const float2* __restrict__ er2,
    const _Float16* __restrict__ feat16, const float* __restrict__ b,
    const _Float16* __restrict__ Wp,
    const float* __restrict__ AL, const float* __restrict__ AR,
    __half2* __restrict__ feat2, float2* __restrict__ el2o, float2* __restrict__ er2o,
    int N) {
    __shared__ int2 stA[4][64], stB[4][64];
    __shared__ float vt[4][64 * 17];   // [wave][feat*17 + node]
    int wave = threadIdx.x >> 6, lane = threadIdx.x & 63, h = lane >> 5;
    int mtile = blockIdx.x * 4 + wave;
    if (mtile * 16 >= N) return;       // no __syncthreads anywhere in this kernel
    int m0 = mtile * 16;
    float bl = b[lane];
    const int2* stH = h ? stB[wave] : stA[wave];
    float* vw = vt[wave];
    // ---- aggregation phase: 16 nodes, one at a time ----
    for (int i = 0; i < 16; i++) {
        int n = m0 + i;
        int2 se = rowse[n];
        int beg = rfl(se.x), end = rfl(se.y);
        float2 rr = er2[n];
        float s = 0.f, acc = 0.f;
        for (int base = beg; base < end; base += 64) {
            int idx = base + lane;
            int sv = 0; float wxv = 0.f, wyv = 0.f;
            if (idx < end) {
                sv = csrc[idx];
                float2 l = el2[sv];
                float t0 = l.x + rr.x; t0 = t0 > 0.f ? t0 : NEG_SLOPE * t0;
                float t1 = l.y + rr.y; t1 = t1 > 0.f ? t1 : NEG_SLOPE * t1;
                wxv = __expf(t0); wyv = __expf(t1);
            }
            stA[wave][lane] = make_int2(sv, __float_as_int(wxv));
            stB[wave][lane] = make_int2(sv, __float_as_int(wyv));
            int cnt = (min(64, end - base) + 15) & ~15;
            for (int j = 0; j < cnt; j += 16) {
                float f[16], w[16];
#pragma unroll
                for (int u = 0; u < 16; u += 2) {
                    int4 e = *(const int4*)(stH + j + u);
                    w[u]     = __int_as_float(e.y);
                    w[u + 1] = __int_as_float(e.w);
                    f[u]     = (float)feat16[(size_t)e.x * 64 + lane];
                    f[u + 1] = (float)feat16[(size_t)e.z * 64 + lane];
                }
                s += ((w[0] + w[1]) + (w[2] + w[3])) + ((w[4] + w[5]) + (w[6] + w[7]));
                s += ((w[8] + w[9]) + (w[10] + w[11])) + ((w[12] + w[13]) + (w[14] + w[15]));
#pragma unroll
                for (int u = 0; u < 16; u++) acc = fmaf(w[u], f[u], acc);
            }
        }
        float v = (s > 0.f) ? acc / s : 0.f;
        v = fmaxf(v + bl, 0.f);
        vw[lane * 17 + i] = v;         // transposed store: 2-way banks (free)
    }
    // ---- MFMA phase: this wave's own 16-row tile ----
    int c = lane & 15, q = lane >> 4;
    v4f acc2[8];
#pragma unroll
    for (int t = 0; t < 8; t++) acc2[t] = (v4f){0.f, 0.f, 0.f, 0.f};
#pragma unroll
    for (int kc = 0; kc < 2; kc++) {
        half8 ah, av;
#pragma unroll
        for (int e = 0; e < 8; e++) {
            float fv = vw[(kc * 32 + q * 8 + e) * 17 + c];
            _Float16 hi = (_Float16)fv;
            ah[e] = hi;
            av[e] = (_Float16)(fv - (float)hi);
        }
#pragma unroll
        for (int t = 0; t < 8; t++) {
            half8 bf = *(const half8*)(Wp + ((size_t)(t * 2 + kc) * 64 + lane) * 8);
            acc2[t] = __builtin_amdgcn_mfma_f32_16x16x32_f16(ah, bf, acc2[t], 0, 0, 0);
            acc2[t] = __builtin_amdgcn_mfma_f32_16x16x32_f16(av, bf, acc2[t], 0, 0, 0);
        }
    }
#pragma unroll
    for (int t = 0; t < 4; t++)
#pragma unroll
        for (int r = 0; r < 4; r++) {
            int row = m0 + q * 4 + r;
            feat2[(size_t)row * 64 + t * 16 + c] =
                __floats2half2_rn(acc2[t][r], acc2[t + 4][r]);
        }
    float alv[8], arv[8];
#pragma unroll
    for (int t = 0; t < 8; t++) { alv[t] = AL[t * 16 + c]; arv[t] = AR[t * 16 + c]; }
#pragma unroll
    for (int r = 0; r < 4; r++) {
        float l0 = 0.f, l1 = 0.f, r0 = 0.f, r1 = 0.f;
#pragma unroll
        for (int t = 0; t < 8; t++) {
            float v = acc2[t][r];
            if (t < 4) { l0 = fmaf(v, alv[t], l0); r0 = fmaf(v, arv[t], r0); }
            else       { l1 = fmaf(v, alv[t], l1); r1 = fmaf(v, arv[t], r1); }
        }
#pragma unroll
        for (int m = 1; m < 16; m <<= 1) {
            l0 += __shfl_xor(l0, m, 64);
            l1 += __shfl_xor(l1, m, 64);
            r0 += __shfl_xor(r0, m, 64);
            r1 += __shfl_xor(r1, m, 64);
        }
        if (c == 0) {
            int row = m0 + q * 4 + r;
            el2o[row] = make_float2(l0, l1);
            er2o[row] = make_float2(r0, r1);
        }
    }
}

// ---------------- agg2: both heads via half2; mean over heads (16-wide) ----------------
__global__ __launch_bounds__(256) void aggregate64_mean(
    const int2* __restrict__ rowse, const int* __restrict__ csrc,
    const float2* __restrict__ el2, const float2* __restrict__ er2,
    const __half2* __restrict__ feat2, const float* __restrict__ b,
    float* __restrict__ out, int N) {
    __shared__ int4 st[4][64];
    int wave = threadIdx.x >> 6, lane = threadIdx.x & 63;
    int n = rfl(blockIdx.x * 4 + wave);
    if (n >= N) return;
    float b0 = b[lane], b1 = b[64 + lane];
    int2 se = rowse[n];
    int beg = rfl(se.x), end = rfl(se.y);
    float2 rr = er2[n];
    float s0 = 0.f, s1 = 0.f, a0 = 0.f, a1 = 0.f;
    for (int base = beg; base < end; base += 64) {
        int idx = base + lane;
        int sv = 0; float wxv = 0.f, wyv = 0.f;
        if (idx < end) {
            sv = csrc[idx];
            float2 l = el2[sv];
            float t0 = l.x + rr.x; t0 = t0 > 0.f ? t0 : NEG_SLOPE * t0;
            float t1 = l.y + rr.y; t1 = t1 > 0.f ? t1 : NEG_SLOPE * t1;
            wxv = __expf(t0); wyv = __expf(t1);
        }
        st[wave][lane] = make_int4(sv, __float_as_int(wxv), __float_as_int(wyv), 0);
        int cnt = (min(64, end - base) + 15) & ~15;   // padded: no scalar tail
        for (int j = 0; j < cnt; j += 16) {
            float2 fv[16]; float wxs[16], wys[16];
#pragma unroll
            for (int u = 0; u < 16; u++) {
                int4 e = st[wave][j + u];
                wxs[u] = __int_as_float(e.y);
                wys[u] = __int_as_float(e.z);
                fv[u] = __half22float2(feat2[(size_t)e.x * 64 + lane]);
            }
#pragma unroll
            for (int u = 0; u < 16; u++) {
                s0 += wxs[u]; s1 += wys[u];
                a0 = fmaf(wxs[u], fv[u].x, a0);
                a1 = fmaf(wys[u], fv[u].y, a1);
            }
        }
    }
    float v0 = (s0 > 0.f) ? a0 / s0 : 0.f;
    float v1 = (s1 > 0.f) ? a1 / s1 : 0.f;
    out[(size_t)n * 64 + lane] = 0.5f * ((v0 + b0) + (v1 + b1));
}

// ---------------- launcher ----------------

extern "C" void kernel_launch(void* const* d_in, const int* in_sizes, int n_in,
                              void* d_out, int out_size, void* d_ws, size_t ws_size,
                              hipStream_t stream) {
    const float* x   = (const float*)d_in[0];
    const int*   src = (const int*)d_in[1];
    const int*   dst = (const int*)d_in[2];
    const float* W0  = (const float*)d_in[3];
    const float* al0 = (const float*)d_in[4];
    const float* ar0 = (const float*)d_in[5];
    const float* b0  = (const float*)d_in[6];
    const float* W1  = (const float*)d_in[7];
    const float* al1 = (const float*)d_in[8];
    const float* ar1 = (const float*)d_in[9];
    const float* b1  = (const float*)d_in[10];
    const float* W2  = (const float*)d_in[11];
    const float* al2 = (const float*)d_in[12];
    const float* ar2 = (const float*)d_in[13];
    const float* b2  = (const float*)d_in[14];
    float* out = (float*)d_out;

    const int N = NNODES;
    const int E = in_sizes[1];

    char* p = (char*)d_ws;
    auto alloc = [&](size_t bytes) {
        void* r = (void*)p;
        p += (bytes + 255) & ~(size_t)255;
        return r;
    };
    int*    bcursor = (int*)alloc((size_t)NBKT * 16 * 4);
    int2*   rowse   = (int2*)alloc((size_t)N * 8);
    int2*   ebuf    = (int2*)alloc(((size_t)NBKT * STRIDE + 4096) * 8);
    int*    csrc    = (int*)alloc(((size_t)NBKT * STRIDE + 4096) * 4);
    float2* el2A    = (float2*)alloc((size_t)N * 8);
    float2* er2A    = (float2*)alloc((size_t)N * 8);
    float2* el2B    = (float2*)alloc((size_t)N * 8);
    float2* er2B    = (float2*)alloc((size_t)N * 8);
    void*   featA   = alloc((size_t)N * 64 * 4);
    _Float16* featB = (_Float16*)alloc((size_t)N * 64 * 2);
    _Float16* Wp2   = (_Float16*)alloc(8 * 2 * 64 * 8 * 2);

    // 0) zero bucket counters (partition counts from zero)
    hipMemsetAsync(bcursor, 0, (size_t)NBKT * 16 * 4, stream);
    // 1) gemm0 + Wp2 pack + partition, one launch (independent jobs overlap)
    int nch = (E + PCHUNK - 1) / PCHUNK;
    kernelAB<<<786 + nch, 256, 0, stream>>>(x, W0, al0, ar0, (_Float16*)featA, el2A, er2A,
                                            W2, Wp2, src, dst, bcursor, ebuf, E, N);
    // 2) local sort -> rowse + csrc (1024 threads/bucket)
    local_sort<<<NBKT, 1024, 0, stream>>>(ebuf, bcursor, rowse, csrc, N);

    int nb4 = (N + 3) / 4;
    // 3) layer-0 aggregate + fused fp32 gemm1 + layer-1 logits
    agg0_gemm1<<<2048, 256, 0, stream>>>(rowse, csrc, el2A, er2A, (const _Float16*)featA,
                                         b0, W1, al1, ar1, featB, el2B, er2B, N);
    // 4+5) FUSED layer-1 aggregate + gemm2 MFMA (64->128)
    int fb = (N / 16 + 3) / 4;
    agg1_gemm2<<<fb, 256, 0, stream>>>(rowse, csrc, el2B, er2B, featB, b1, Wp2, al2, ar2,
                                       (__half2*)featA, el2A, er2A, N);
    // 6) layer-2 aggregate, mean over heads
    aggregate64_mean<<<nb4, 256, 0, stream>>>(rowse, csrc, el2A, er2A, (const __half2*)featA,
                                              b2, out, N);
}

// Round 3
// 238.638 us; speedup vs baseline: 1.1104x; 1.1104x over previous
//
#include <hip/hip_runtime.h>
#include <hip/hip_bf16.h>
#include <hip/hip_fp16.h>

#define NNODES 50000
#define NEG_SLOPE 0.2f
#define BKT_SHIFT 8
#define NBKT ((NNODES + 255) >> 8)   // 196 buckets of 256 dsts
#define STRIDE 5120                   // fixed slots per bucket (avg 4082, +16 sigma)
#define PCHUNK 2048                   // partition chunk (256 thr x 8 edges)
#define PEPT 8

typedef _Float16 half8 __attribute__((ext_vector_type(8)));
typedef float v4f __attribute__((ext_vector_type(4)));

__device__ __forceinline__ int rfl(int v) { return __builtin_amdgcn_readfirstlane(v); }

// pack W[K][C] fp32 into MFMA B-fragment order
__device__ __forceinline__ void pack_one(const float* W, _Float16* Wp, int K, int C, int tid) {
    int KC = K / 32;
    int l = tid & 63;
    int kc = (tid >> 6) % KC;
    int t = tid / (KC * 64);
    int cc = l & 15, q = l >> 4;
    half8 b;
#pragma unroll
    for (int j = 0; j < 8; j++)
        b[j] = (_Float16)W[(size_t)(kc * 32 + q * 8 + j) * C + t * 16 + cc];
    *(half8*)(Wp + (size_t)tid * 8) = b;
}

// ---------------- Kernel AB: gemm0 + Wp2 pack + edge partition, ONE launch ----------
__global__ __launch_bounds__(256) void kernelAB(
    const float* __restrict__ x, const float* __restrict__ W0,
    const float* __restrict__ AL, const float* __restrict__ AR,
    _Float16* __restrict__ featA, float2* __restrict__ el2A, float2* __restrict__ er2A,
    const float* __restrict__ W2, _Float16* __restrict__ Wp2,
    const int* __restrict__ src, const int* __restrict__ dst,
    int* __restrict__ bcursor, int2* __restrict__ ebuf, int E, int N) {
    int blk = blockIdx.x;
    if (blk >= 786) {
        // ---- partition branch ----
        __shared__ int hist[NBKT];
        __shared__ int gbase[NBKT];
        int t = threadIdx.x;
        for (int i = t; i < NBKT; i += 256) hist[i] = 0;
        __syncthreads();
        int base = (blk - 786) * PCHUNK;
        int sreg[PEPT], dreg[PEPT], rreg[PEPT], breg[PEPT];
#pragma unroll
        for (int k = 0; k < PEPT; k++) {
            int i = base + k * 256 + t;
            if (i < E) {
                sreg[k] = src[i];
                dreg[k] = dst[i];
                breg[k] = dreg[k] >> BKT_SHIFT;
                rreg[k] = atomicAdd(&hist[breg[k]], 1);
            } else {
                breg[k] = -1;
            }
        }
        __syncthreads();
        for (int i = t; i < NBKT; i += 256)
            if (hist[i]) gbase[i] = i * STRIDE + atomicAdd(&bcursor[i * 16], hist[i]);
        __syncthreads();
#pragma unroll
        for (int k = 0; k < PEPT; k++) {
            if (breg[k] >= 0)
                ebuf[(size_t)(gbase[breg[k]] + rreg[k])] = make_int2(sreg[k], dreg[k]);
        }
        return;
    }
    if (blk >= 782) {
        int tid = (blk - 782) * 256 + threadIdx.x;
        if (tid < 8 * 2 * 64) pack_one(W2, Wp2, 64, 128, tid);
        return;
    }
    // ---- gemm0 branch ----
    int wave = threadIdx.x >> 6, lane = threadIdx.x & 63;
    int mtile = blk * 4 + wave;
    if (mtile * 16 >= N) return;
    int m0 = mtile * 16;
    int c = lane & 15, q = lane >> 4;
    v4f acc[4];
#pragma unroll
    for (int t = 0; t < 4; t++) acc[t] = (v4f){0.f, 0.f, 0.f, 0.f};
    const size_t arow = (size_t)(m0 + c) * 128 + q * 8;
#pragma unroll
    for (int kc = 0; kc < 4; kc++) {
        const float* xr = x + arow + kc * 32;
        float4 f0 = *(const float4*)xr;
        float4 f1 = *(const float4*)(xr + 4);
        float fv[8] = {f0.x, f0.y, f0.z, f0.w, f1.x, f1.y, f1.z, f1.w};
        half8 ah, av;
#pragma unroll
        for (int j = 0; j < 8; j++) {
            ah[j] = (_Float16)fv[j];
            av[j] = (_Float16)(fv[j] - (float)ah[j]);
        }
#pragma unroll
        for (int tt = 0; tt < 4; tt++) {
            half8 b;
#pragma unroll
            for (int j = 0; j < 8; j++)
                b[j] = (_Float16)W0[(size_t)(kc * 32 + q * 8 + j) * 64 + tt * 16 + c];
            acc[tt] = __builtin_amdgcn_mfma_f32_16x16x32_f16(ah, b, acc[tt], 0, 0, 0);
            acc[tt] = __builtin_amdgcn_mfma_f32_16x16x32_f16(av, b, acc[tt], 0, 0, 0);
        }
    }
#pragma unroll
    for (int tt = 0; tt < 4; tt++)
#pragma unroll
        for (int r = 0; r < 4; r++) {
            int row = m0 + q * 4 + r;
            featA[(size_t)row * 64 + tt * 16 + c] = (_Float16)acc[tt][r];
        }
    float alv[4], arv[4];
#pragma unroll
    for (int tt = 0; tt < 4; tt++) { alv[tt] = AL[tt * 16 + c]; arv[tt] = AR[tt * 16 + c]; }
#pragma unroll
    for (int r = 0; r < 4; r++) {
        float l0 = 0.f, l1 = 0.f, r0 = 0.f, r1 = 0.f;
#pragma unroll
        for (int tt = 0; tt < 4; tt++) {
            float v = acc[tt][r];
            if (tt < 2) { l0 = fmaf(v, alv[tt], l0); r0 = fmaf(v, arv[tt], r0); }
            else        { l1 = fmaf(v, alv[tt], l1); r1 = fmaf(v, arv[tt], r1); }
        }
#pragma unroll
        for (int m = 1; m < 16; m <<= 1) {
            l0 += __shfl_xor(l0, m, 64);
            l1 += __shfl_xor(l1, m, 64);
            r0 += __shfl_xor(r0, m, 64);
            r1 += __shfl_xor(r1, m, 64);
        }
        if (c == 0) {
            int row = m0 + q * 4 + r;
            el2A[row] = make_float2(l0, l1);
            er2A[row] = make_float2(r0, r1);
        }
    }
}

// ---------------- local sort: 1024 threads/bucket (4x parallel vs 256) ----
__global__ __launch_bounds__(1024) void local_sort(const int2* __restrict__ ebuf,
                                                   const int* __restrict__ bcursor,
                                                   int2* __restrict__ rowse,
                                                   int* __restrict__ csrc, int N) {
    __shared__ int lcnt[256], lrow[256], ws[4];
    int b = blockIdx.x;
    int d0 = b << BKT_SHIFT;
    int t = threadIdx.x;
    int base = b * STRIDE;
    int endE = base + bcursor[b * 16];
    if (t < 256) lcnt[t] = 0;
    __syncthreads();
    for (int i = base + t; i < endE; i += 1024)
        atomicAdd(&lcnt[ebuf[i].y - d0], 1);
    __syncthreads();
    int v = (t < 256) ? lcnt[t] : 0;
    int lane = t & 63;
    int x = v;
#pragma unroll
    for (int m = 1; m < 64; m <<= 1) {
        int y = __shfl_up(x, m, 64);
        if (lane >= m) x += y;
    }
    if (t < 256 && lane == 63) ws[t >> 6] = x;
    __syncthreads();
    if (t < 256) {
        int w = t >> 6, waveoff = 0;
#pragma unroll
        for (int k = 0; k < 4; k++) if (k < w) waveoff += ws[k];
        int excl = base + waveoff + x - v;
        lrow[t] = excl;
        int d = d0 + t;
        if (d < N) rowse[d] = make_int2(excl, excl + v);
        lcnt[t] = 0;
    }
    __syncthreads();
    for (int i = base + t; i < endE; i += 1024) {
        int2 e = ebuf[i];
        int ld = e.y - d0;
        int p = lrow[ld] + atomicAdd(&lcnt[ld], 1);
        csrc[p] = e.x;
    }
}

// ---------------- agg0 + fused fp32 matvec gemm1 (64->64) + layer-1 logits ----
// 16-wide gather groups: one full latency exposure per average-degree node.
// s-summation keeps the original pairwise-8 order (bit-identical).
__global__ __launch_bounds__(256) void agg0_gemm1(
    const int2* __restrict__ rowse, const int* __restrict__ csrc,
    const float2* __restrict__ el2A, const float2* __restrict__ er2A,
    const _Float16* __restrict__ featA, const float* __restrict__ b0,
    const float* __restrict__ W1, const float* __restrict__ al1, const float* __restrict__ ar1,
    _Float16* __restrict__ featB, float2* __restrict__ el2B, float2* __restrict__ er2B,
    int N) {
    __shared__ int2 stA[4][64], stB[4][64];
    __shared__ float vbuf[4][64];
    __shared__ float4 w1v[16 * 64];   // [k4][lane] -> (W1[4k4+0..3][lane])
    int wave = threadIdx.x >> 6, lane = threadIdx.x & 63, h = lane >> 5;
    for (int i = threadIdx.x; i < 64 * 64; i += 256) {
        int k = i >> 6, cc = i & 63;
        ((float*)w1v)[((((k >> 2) << 6) + cc) << 2) | (k & 3)] = W1[i];
    }
    __syncthreads();
    float bl = b0[lane];
    float al1v = al1[lane], ar1v = ar1[lane];
    const int2* stH = h ? stB[wave] : stA[wave];
    for (int n0 = blockIdx.x * 4 + wave; n0 < N; n0 += gridDim.x * 4) {
        int n = rfl(n0);
        int2 se = rowse[n];
        int beg = rfl(se.x), end = rfl(se.y);
        float2 rr = er2A[n];
        float s = 0.f, acc = 0.f;
        for (int base = beg; base < end; base += 64) {
            int idx = base + lane;
            int sv = 0; float wxv = 0.f, wyv = 0.f;
            if (idx < end) {
                sv = csrc[idx];
                float2 l = el2A[sv];
                float t0 = l.x + rr.x; t0 = t0 > 0.f ? t0 : NEG_SLOPE * t0;
                float t1 = l.y + rr.y; t1 = t1 > 0.f ? t1 : NEG_SLOPE * t1;
                wxv = __expf(t0); wyv = __expf(t1);
            }
            stA[wave][lane] = make_int2(sv, __float_as_int(wxv));
            stB[wave][lane] = make_int2(sv, __float_as_int(wyv));
            int cnt = (min(64, end - base) + 15) & ~15;   // padded: no scalar tail
            for (int j = 0; j < cnt; j += 16) {
                float f[16], w[16];
#pragma unroll
                for (int u = 0; u < 16; u += 2) {
                    int4 e = *(const int4*)(stH + j + u);
                    w[u]     = __int_as_float(e.y);
                    w[u + 1] = __int_as_float(e.w);
                    f[u]     = (float)featA[(size_t)e.x * 64 + lane];
                    f[u + 1] = (float)featA[(size_t)e.z * 64 + lane];
                }
                s += ((w[0] + w[1]) + (w[2] + w[3])) + ((w[4] + w[5]) + (w[6] + w[7]));
                s += ((w[8] + w[9]) + (w[10] + w[11])) + ((w[12] + w[13]) + (w[14] + w[15]));
#pragma unroll
                for (int u = 0; u < 16; u++) acc = fmaf(w[u], f[u], acc);
            }
        }
        float v = (s > 0.f) ? acc / s : 0.f;
        v = fmaxf(v + bl, 0.f);
        vbuf[wave][lane] = v;
        const float4* vv = (const float4*)vbuf[wave];
        float f = 0.f;
#pragma unroll
        for (int kk = 0; kk < 16; kk++) {
            float4 v4 = vv[kk];                 // LDS broadcast (same addr all lanes)
            float4 w4 = w1v[(kk << 6) + lane];  // contiguous b128, conflict-free
            f = fmaf(v4.x, w4.x, f);
            f = fmaf(v4.y, w4.y, f);
            f = fmaf(v4.z, w4.z, f);
            f = fmaf(v4.w, w4.w, f);
        }
        featB[(size_t)n * 64 + lane] = (_Float16)f;
        float vl = f * al1v, vr = f * ar1v;
#pragma unroll
        for (int m = 1; m < 32; m <<= 1) {
            vl += __shfl_xor(vl, m, 64);
            vr += __shfl_xor(vr, m, 64);
        }
        if ((lane & 31) == 0) {
            ((float*)el2B)[n * 2 + h] = vl;
            ((float*)er2B)[n * 2 + h] = vr;
        }
    }
}

// ---------------- agg1 (layer 1): outputs hi/lo fp16 for MFMA gemm2 ----------------
__global__ __launch_bounds__(256) void aggregate32(
    const int2* __restrict__ rowse, const int* __restrict__ csrc,
    const float2* __restrict__ el2, const float2* __restrict__ er2,
    const _Float16* __restrict__ feat16, const float* __restrict__ b,
    _Float16* __restrict__ ahi, _Float16* __restrict__ alo, int N) {
    __shared__ int2 stA[4][64], stB[4][64];
    int wave = threadIdx.x >> 6, lane = threadIdx.x & 63, h = lane >> 5;
    int n = rfl(blockIdx.x * 4 + wave);
    if (n >= N) return;
    float bl = b[lane];
    int2 se = rowse[n];
    int beg = rfl(se.x), end = rfl(se.y);
    float2 rr = er2[n];
    const int2* stH = h ? stB[wave] : stA[wave];
    float s = 0.f, acc = 0.f;
    for (int base = beg; base < end; base += 64) {
        int idx = base + lane;
        int sv = 0; float wxv = 0.f, wyv = 0.f;
        if (idx < end) {
            sv = csrc[idx];
            float2 l = el2[sv];
            float t0 = l.x + rr.x; t0 = t0 > 0.f ? t0 : NEG_SLOPE * t0;
            float t1 = l.y + rr.y; t1 = t1 > 0.f ? t1 : NEG_SLOPE * t1;
            wxv = __expf(t0); wyv = __expf(t1);
        }
        stA[wave][lane] = make_int2(sv, __float_as_int(wxv));
        stB[wave][lane] = make_int2(sv, __float_as_int(wyv));
        int cnt = (min(64, end - base) + 15) & ~15;   // padded: no scalar tail
        for (int j = 0; j < cnt; j += 16) {
            float f[16], w[16];
#pragma unroll
            for (int u = 0; u < 16; u += 2) {
                int4 e = *(const int4*)(stH + j + u);
                w[u]     = __int_as_float(e.y);
                w[u + 1] = __int_as_float(e.w);
                f[u]     = (float)feat16[(size_t)e.x * 64 + lane];
                f[u + 1] = (float)feat16[(size_t)e.z * 64 + lane];
            }
            s += ((w[0] + w[1]) + (w[2] + w[3])) + ((w[4] + w[5]) + (w[6] + w[7]));
            s += ((w[8] + w[9]) + (w[10] + w[11])) + ((w[12] + w[13]) + (w[14] + w[15]));
#pragma unroll
            for (int u = 0; u < 16; u++) acc = fmaf(w[u], f[u], acc);
        }
    }
    float v = (s > 0.f) ? acc / s : 0.f;
    v = fmaxf(v + bl, 0.f);
    _Float16 hv = (_Float16)v;
    ahi[(size_t)n * 64 + lane] = hv;
    alo[(size_t)n * 64 + lane] = (_Float16)(v - (float)hv);
}

// ---------------- gemm2: MFMA 64->128, half2-interleaved feat + layer-2 logits ----
__global__ __launch_bounds__(256) void gemm_mfma2(
    const _Float16* __restrict__ Ahi, const _Float16* __restrict__ Alo,
    const _Float16* __restrict__ Wp,
    const float* __restrict__ AL, const float* __restrict__ AR,
    __half2* __restrict__ feat2, float2* __restrict__ el2, float2* __restrict__ er2,
    int N) {
    constexpr int KC = 2, NT = 8;
    int wave = threadIdx.x >> 6, lane = threadIdx.x & 63;
    int mtile = blockIdx.x * 4 + wave;
    if (mtile * 16 >= N) return;
    int m0 = mtile * 16;
    int c = lane & 15, q = lane >> 4;
    v4f acc[NT];
#pragma unroll
    for (int t = 0; t < NT; t++) acc[t] = (v4f){0.f, 0.f, 0.f, 0.f};
    const size_t arow = (size_t)(m0 + c) * 64 + q * 8;
#pragma unroll
    for (int kc = 0; kc < KC; kc++) {
        half8 ah = *(const half8*)(Ahi + arow + kc * 32);
        half8 av = *(const half8*)(Alo + arow + kc * 32);
#pragma unroll
        for (int t = 0; t < NT; t++) {
            half8 b = *(const half8*)(Wp + ((size_t)(t * KC + kc) * 64 + lane) * 8);
            acc[t] = __builtin_amdgcn_mfma_f32_16x16x32_f16(ah, b, acc[t], 0, 0, 0);
            acc[t] = __builtin_amdgcn_mfma_f32_16x16x32_f16(av, b, acc[t], 0, 0, 0);
        }
    }
#pragma unroll
    for (int t = 0; t < NT / 2; t++)
#pragma unroll
        for (int r = 0; r < 4; r++) {
            int row = m0 + q * 4 + r;
            feat2[(size_t)row * 64 + t * 16 + c] =
                __floats2half2_rn(acc[t][r], acc[t + NT / 2][r]);
        }
    float alv[NT], arv[NT];
#pragma unroll
    for (int t = 0; t < NT; t++) { alv[t] = AL[t * 16 + c]; arv[t] = AR[t * 16 + c]; }
#pragma unroll
    for (int r = 0; r < 4; r++) {
        float l0 = 0.f, l1 = 0.f, r0 = 0.f, r1 = 0.f;
#pragma unroll
        for (int t = 0; t < NT; t++) {
            float v = acc[t][r];
            if (t < NT / 2) { l0 = fmaf(v, alv[t], l0); r0 = fmaf(v, arv[t], r0); }
            else            { l1 = fmaf(v, alv[t], l1); r1 = fmaf(v, arv[t], r1); }
        }
#pragma unroll
        for (int m = 1; m < 16; m <<= 1) {
            l0 += __shfl_xor(l0, m, 64);
            l1 += __shfl_xor(l1, m, 64);
            r0 += __shfl_xor(r0, m, 64);
            r1 += __shfl_xor(r1, m, 64);
        }
        if (c == 0) {
            int row = m0 + q * 4 + r;
            el2[row] = make_float2(l0, l1);
            er2[row] = make_float2(r0, r1);
        }
    }
}

// ---------------- agg2: both heads via half2; mean over heads (16-wide) ----------------
__global__ __launch_bounds__(256) void aggregate64_mean(
    const int2* __restrict__ rowse, const int* __restrict__ csrc,
    const float2* __restrict__ el2, const float2* __restrict__ er2,
    const __half2* __restrict__ feat2, const float* __restrict__ b,
    float* __restrict__ out, int N) {
    __shared__ int4 st[4][64];
    int wave = threadIdx.x >> 6, lane = threadIdx.x & 63;
    int n = rfl(blockIdx.x * 4 + wave);
    if (n >= N) return;
    float b0 = b[lane], b1 = b[64 + lane];
    int2 se = rowse[n];
    int beg = rfl(se.x), end = rfl(se.y);
    float2 rr = er2[n];
    float s0 = 0.f, s1 = 0.f, a0 = 0.f, a1 = 0.f;
    for (int base = beg; base < end; base += 64) {
        int idx = base + lane;
        int sv = 0; float wxv = 0.f, wyv = 0.f;
        if (idx < end) {
            sv = csrc[idx];
            float2 l = el2[sv];
            float t0 = l.x + rr.x; t0 = t0 > 0.f ? t0 : NEG_SLOPE * t0;
            float t1 = l.y + rr.y; t1 = t1 > 0.f ? t1 : NEG_SLOPE * t1;
            wxv = __expf(t0); wyv = __expf(t1);
        }
        st[wave][lane] = make_int4(sv, __float_as_int(wxv), __float_as_int(wyv), 0);
        int cnt = (min(64, end - base) + 15) & ~15;   // padded: no scalar tail
        for (int j = 0; j < cnt; j += 16) {
            float2 fv[16]; float wxs[16], wys[16];
#pragma unroll
            for (int u = 0; u < 16; u++) {
                int4 e = st[wave][j + u];
                wxs[u] = __int_as_float(e.y);
                wys[u] = __int_as_float(e.z);
                fv[u] = __half22float2(feat2[(size_t)e.x * 64 + lane]);
            }
#pragma unroll
            for (int u = 0; u < 16; u++) {
                s0 += wxs[u]; s1 += wys[u];
                a0 = fmaf(wxs[u], fv[u].x, a0);
                a1 = fmaf(wys[u], fv[u].y, a1);
            }
        }
    }
    float v0 = (s0 > 0.f) ? a0 / s0 : 0.f;
    float v1 = (s1 > 0.f) ? a1 / s1 : 0.f;
    out[(size_t)n * 64 + lane] = 0.5f * ((v0 + b0) + (v1 + b1));
}

// ---------------- launcher ----------------

extern "C" void kernel_launch(void* const* d_in, const int* in_sizes, int n_in,
                              void* d_out, int out_size, void* d_ws, size_t ws_size,
                              hipStream_t stream) {
    const float* x   = (const float*)d_in[0];
    const int*   src = (const int*)d_in[1];
    const int*   dst = (const int*)d_in[2];
    const float* W0  = (const float*)d_in[3];
    const float* al0 = (const float*)d_in[4];
    const float* ar0 = (const float*)d_in[5];
    const float* b0  = (const float*)d_in[6];
    const float* W1  = (const float*)d_in[7];
    const float* al1 = (const float*)d_in[8];
    const float* ar1 = (const float*)d_in[9];
    const float* b1  = (const float*)d_in[10];
    const float* W2  = (const float*)d_in[11];
    const float* al2 = (const float*)d_in[12];
    const float* ar2 = (const float*)d_in[13];
    const float* b2  = (const float*)d_in[14];
    float* out = (float*)d_out;

    const int N = NNODES;
    const int E = in_sizes[1];

    char* p = (char*)d_ws;
    auto alloc = [&](size_t bytes) {
        void* r = (void*)p;
        p += (bytes + 255) & ~(size_t)255;
        return r;
    };
    int*    bcursor = (int*)alloc((size_t)NBKT * 16 * 4);
    int2*   rowse   = (int2*)alloc((size_t)N * 8);
    int2*   ebuf    = (int2*)alloc(((size_t)NBKT * STRIDE + 4096) * 8);
    int*    csrc    = (int*)alloc(((size_t)NBKT * STRIDE + 4096) * 4);
    float2* el2A    = (float2*)alloc((size_t)N * 8);
    float2* er2A    = (float2*)alloc((size_t)N * 8);
    float2* el2B    = (float2*)alloc((size_t)N * 8);
    float2* er2B    = (float2*)alloc((size_t)N * 8);
    _Float16* ahi   = (_Float16*)alloc((size_t)N * 64 * 2);
    _Float16* alo   = (_Float16*)alloc((size_t)N * 64 * 2);
    void*   featA   = alloc((size_t)N * 64 * 4);
    _Float16* featB = (_Float16*)alloc((size_t)N * 64 * 2);
    _Float16* Wp2   = (_Float16*)alloc(8 * 2 * 64 * 8 * 2);

    // 0) zero bucket counters (partition counts from zero)
    hipMemsetAsync(bcursor, 0, (size_t)NBKT * 16 * 4, stream);
    // 1) gemm0 + Wp2 pack + partition, one launch (independent jobs overlap)
    int nch = (E + PCHUNK - 1) / PCHUNK;
    kernelAB<<<786 + nch, 256, 0, stream>>>(x, W0, al0, ar0, (_Float16*)featA, el2A, er2A,
                                            W2, Wp2, src, dst, bcursor, ebuf, E, N);
    // 2) local sort -> rowse + csrc (1024 threads/bucket)
    local_sort<<<NBKT, 1024, 0, stream>>>(ebuf, bcursor, rowse, csrc, N);

    int nb4 = (N + 3) / 4;
    // 3) layer-0 aggregate + fused fp32 gemm1 + layer-1 logits
    agg0_gemm1<<<2048, 256, 0, stream>>>(rowse, csrc, el2A, er2A, (const _Float16*)featA,
                                         b0, W1, al1, ar1, featB, el2B, er2B, N);
    // 4) layer-1 aggregate -> hi/lo fp16
    aggregate32<<<nb4, 256, 0, stream>>>(rowse, csrc, el2B, er2B, featB, b1, ahi, alo, N);
    // 5) gemm2 MFMA (64->128)
    int gb = (N / 16 + 3) / 4;
    gemm_mfma2<<<gb, 256, 0, stream>>>(ahi, alo, Wp2, al2, ar2, (__half2*)featA, el2A, er2A, N);
    // 6) layer-2 aggregate, mean over heads
    aggregate64_mean<<<nb4, 256, 0, stream>>>(rowse, csrc, el2A, er2A, (const __half2*)featA,
                                              b2, out, N);
}

// Round 4
// 226.094 us; speedup vs baseline: 1.1720x; 1.0555x over previous
//
#include <hip/hip_runtime.h>
#include <hip/hip_bf16.h>
#include <hip/hip_fp16.h>

#define NNODES 50000
#define NEG_SLOPE 0.2f
#define BKT_SHIFT 8
#define NBKT ((NNODES + 255) >> 8)   // 196 buckets of 256 dsts
#define STRIDE 5120                   // fixed slots per bucket (avg 4082, +16 sigma)
#define PCHUNK 2048                   // partition chunk (256 thr x 8 edges)
#define PEPT 8

typedef _Float16 half8 __attribute__((ext_vector_type(8)));
typedef float v4f __attribute__((ext_vector_type(4)));

__device__ __forceinline__ int rfl(int v) { return __builtin_amdgcn_readfirstlane(v); }

// pack W[K][C] fp32 into MFMA B-fragment order
__device__ __forceinline__ void pack_one(const float* W, _Float16* Wp, int K, int C, int tid) {
    int KC = K / 32;
    int l = tid & 63;
    int kc = (tid >> 6) % KC;
    int t = tid / (KC * 64);
    int cc = l & 15, q = l >> 4;
    half8 b;
#pragma unroll
    for (int j = 0; j < 8; j++)
        b[j] = (_Float16)W[(size_t)(kc * 32 + q * 8 + j) * C + t * 16 + cc];
    *(half8*)(Wp + (size_t)tid * 8) = b;
}

// ---------------- Kernel AB: gemm0 + Wp2 pack + edge partition, ONE launch ----------
__global__ __launch_bounds__(256) void kernelAB(
    const float* __restrict__ x, const float* __restrict__ W0,
    const float* __restrict__ AL, const float* __restrict__ AR,
    _Float16* __restrict__ featA, float2* __restrict__ el2A, float2* __restrict__ er2A,
    const float* __restrict__ W2, _Float16* __restrict__ Wp2,
    const int* __restrict__ src, const int* __restrict__ dst,
    int* __restrict__ bcursor, int2* __restrict__ ebuf, int E, int N) {
    int blk = blockIdx.x;
    if (blk >= 786) {
        // ---- partition branch ----
        __shared__ int hist[NBKT];
        __shared__ int gbase[NBKT];
        int t = threadIdx.x;
        for (int i = t; i < NBKT; i += 256) hist[i] = 0;
        __syncthreads();
        int base = (blk - 786) * PCHUNK;
        int sreg[PEPT], dreg[PEPT], rreg[PEPT], breg[PEPT];
#pragma unroll
        for (int k = 0; k < PEPT; k++) {
            int i = base + k * 256 + t;
            if (i < E) {
                sreg[k] = src[i];
                dreg[k] = dst[i];
                breg[k] = dreg[k] >> BKT_SHIFT;
                rreg[k] = atomicAdd(&hist[breg[k]], 1);
            } else {
                breg[k] = -1;
            }
        }
        __syncthreads();
        for (int i = t; i < NBKT; i += 256)
            if (hist[i]) gbase[i] = i * STRIDE + atomicAdd(&bcursor[i * 16], hist[i]);
        __syncthreads();
#pragma unroll
        for (int k = 0; k < PEPT; k++) {
            if (breg[k] >= 0)
                ebuf[(size_t)(gbase[breg[k]] + rreg[k])] = make_int2(sreg[k], dreg[k]);
        }
        return;
    }
    if (blk >= 782) {
        int tid = (blk - 782) * 256 + threadIdx.x;
        if (tid < 8 * 2 * 64) pack_one(W2, Wp2, 64, 128, tid);
        return;
    }
    // ---- gemm0 branch ----
    int wave = threadIdx.x >> 6, lane = threadIdx.x & 63;
    int mtile = blk * 4 + wave;
    if (mtile * 16 >= N) return;
    int m0 = mtile * 16;
    int c = lane & 15, q = lane >> 4;
    v4f acc[4];
#pragma unroll
    for (int t = 0; t < 4; t++) acc[t] = (v4f){0.f, 0.f, 0.f, 0.f};
    const size_t arow = (size_t)(m0 + c) * 128 + q * 8;
#pragma unroll
    for (int kc = 0; kc < 4; kc++) {
        const float* xr = x + arow + kc * 32;
        float4 f0 = *(const float4*)xr;
        float4 f1 = *(const float4*)(xr + 4);
        float fv[8] = {f0.x, f0.y, f0.z, f0.w, f1.x, f1.y, f1.z, f1.w};
        half8 ah, av;
#pragma unroll
        for (int j = 0; j < 8; j++) {
            ah[j] = (_Float16)fv[j];
            av[j] = (_Float16)(fv[j] - (float)ah[j]);
        }
#pragma unroll
        for (int tt = 0; tt < 4; tt++) {
            half8 b;
#pragma unroll
            for (int j = 0; j < 8; j++)
                b[j] = (_Float16)W0[(size_t)(kc * 32 + q * 8 + j) * 64 + tt * 16 + c];
            acc[tt] = __builtin_amdgcn_mfma_f32_16x16x32_f16(ah, b, acc[tt], 0, 0, 0);
            acc[tt] = __builtin_amdgcn_mfma_f32_16x16x32_f16(av, b, acc[tt], 0, 0, 0);
        }
    }
#pragma unroll
    for (int tt = 0; tt < 4; tt++)
#pragma unroll
        for (int r = 0; r < 4; r++) {
            int row = m0 + q * 4 + r;
            featA[(size_t)row * 64 + tt * 16 + c] = (_Float16)acc[tt][r];
        }
    float alv[4], arv[4];
#pragma unroll
    for (int tt = 0; tt < 4; tt++) { alv[tt] = AL[tt * 16 + c]; arv[tt] = AR[tt * 16 + c]; }
#pragma unroll
    for (int r = 0; r < 4; r++) {
        float l0 = 0.f, l1 = 0.f, r0 = 0.f, r1 = 0.f;
#pragma unroll
        for (int tt = 0; tt < 4; tt++) {
            float v = acc[tt][r];
            if (tt < 2) { l0 = fmaf(v, alv[tt], l0); r0 = fmaf(v, arv[tt], r0); }
            else        { l1 = fmaf(v, alv[tt], l1); r1 = fmaf(v, arv[tt], r1); }
        }
#pragma unroll
        for (int m = 1; m < 16; m <<= 1) {
            l0 += __shfl_xor(l0, m, 64);
            l1 += __shfl_xor(l1, m, 64);
            r0 += __shfl_xor(r0, m, 64);
            r1 += __shfl_xor(r1, m, 64);
        }
        if (c == 0) {
            int row = m0 + q * 4 + r;
            el2A[row] = make_float2(l0, l1);
            er2A[row] = make_float2(r0, r1);
        }
    }
}

// ---------------- local sort: 1024 threads/bucket ----
__global__ __launch_bounds__(1024) void local_sort(const int2* __restrict__ ebuf,
                                                   const int* __restrict__ bcursor,
                                                   int2* __restrict__ rowse,
                                                   int* __restrict__ csrc, int N) {
    __shared__ int lcnt[256], lrow[256], ws[4];
    int b = blockIdx.x;
    int d0 = b << BKT_SHIFT;
    int t = threadIdx.x;
    int base = b * STRIDE;
    int endE = base + bcursor[b * 16];
    if (t < 256) lcnt[t] = 0;
    __syncthreads();
    for (int i = base + t; i < endE; i += 1024)
        atomicAdd(&lcnt[ebuf[i].y - d0], 1);
    __syncthreads();
    int v = (t < 256) ? lcnt[t] : 0;
    int lane = t & 63;
    int x = v;
#pragma unroll
    for (int m = 1; m < 64; m <<= 1) {
        int y = __shfl_up(x, m, 64);
        if (lane >= m) x += y;
    }
    if (t < 256 && lane == 63) ws[t >> 6] = x;
    __syncthreads();
    if (t < 256) {
        int w = t >> 6, waveoff = 0;
#pragma unroll
        for (int k = 0; k < 4; k++) if (k < w) waveoff += ws[k];
        int excl = base + waveoff + x - v;
        lrow[t] = excl;
        int d = d0 + t;
        if (d < N) rowse[d] = make_int2(excl, excl + v);
        lcnt[t] = 0;
    }
    __syncthreads();
    for (int i = base + t; i < endE; i += 1024) {
        int2 e = ebuf[i];
        int ld = e.y - d0;
        int p = lrow[ld] + atomicAdd(&lcnt[ld], 1);
        csrc[p] = e.x;
    }
}

// ---------------- agg0 + fused fp32 matvec gemm1 (64->64) + layer-1 logits ----
// 8-wide gather groups (matches Poisson-16 degree dist; 16-wide regressed r3).
__global__ __launch_bounds__(256) void agg0_gemm1(
    const int2* __restrict__ rowse, const int* __restrict__ csrc,
    const float2* __restrict__ el2A, const float2* __restrict__ er2A,
    const _Float16* __restrict__ featA, const float* __restrict__ b0,
    const float* __restrict__ W1, const float* __restrict__ al1, const float* __restrict__ ar1,
    _Float16* __restrict__ featB, float2* __restrict__ el2B, float2* __restrict__ er2B,
    int N) {
    __shared__ int2 stA[4][64], stB[4][64];
    __shared__ float vbuf[4][64];
    __shared__ float4 w1v[16 * 64];   // [k4][lane] -> (W1[4k4+0..3][lane])
    int wave = threadIdx.x >> 6, lane = threadIdx.x & 63, h = lane >> 5;
    for (int i = threadIdx.x; i < 64 * 64; i += 256) {
        int k = i >> 6, cc = i & 63;
        ((float*)w1v)[((((k >> 2) << 6) + cc) << 2) | (k & 3)] = W1[i];
    }
    __syncthreads();
    float bl = b0[lane];
    float al1v = al1[lane], ar1v = ar1[lane];
    const int2* stH = h ? stB[wave] : stA[wave];
    for (int n0 = blockIdx.x * 4 + wave; n0 < N; n0 += gridDim.x * 4) {
        int n = rfl(n0);
        int2 se = rowse[n];
        int beg = rfl(se.x), end = rfl(se.y);
        float2 rr = er2A[n];
        float s = 0.f, acc = 0.f;
        for (int base = beg; base < end; base += 64) {
            int idx = base + lane;
            int sv = 0; float wxv = 0.f, wyv = 0.f;
            if (idx < end) {
                sv = csrc[idx];
                float2 l = el2A[sv];
                float t0 = l.x + rr.x; t0 = t0 > 0.f ? t0 : NEG_SLOPE * t0;
                float t1 = l.y + rr.y; t1 = t1 > 0.f ? t1 : NEG_SLOPE * t1;
                wxv = __expf(t0); wyv = __expf(t1);
            }
            stA[wave][lane] = make_int2(sv, __float_as_int(wxv));
            stB[wave][lane] = make_int2(sv, __float_as_int(wyv));
            int cnt = (min(64, end - base) + 7) & ~7;   // padded: no scalar tail
            for (int j = 0; j < cnt; j += 8) {
                int4 e01 = *(const int4*)(stH + j);
                int4 e23 = *(const int4*)(stH + j + 2);
                int4 e45 = *(const int4*)(stH + j + 4);
                int4 e67 = *(const int4*)(stH + j + 6);
                float f0 = (float)featA[(size_t)e01.x * 64 + lane];
                float f1 = (float)featA[(size_t)e01.z * 64 + lane];
                float f2 = (float)featA[(size_t)e23.x * 64 + lane];
                float f3 = (float)featA[(size_t)e23.z * 64 + lane];
                float f4 = (float)featA[(size_t)e45.x * 64 + lane];
                float f5 = (float)featA[(size_t)e45.z * 64 + lane];
                float f6 = (float)featA[(size_t)e67.x * 64 + lane];
                float f7 = (float)featA[(size_t)e67.z * 64 + lane];
                float w0 = __int_as_float(e01.y), w1 = __int_as_float(e01.w);
                float w2 = __int_as_float(e23.y), w3 = __int_as_float(e23.w);
                float w4 = __int_as_float(e45.y), w5 = __int_as_float(e45.w);
                float w6 = __int_as_float(e67.y), w7 = __int_as_float(e67.w);
                s += ((w0 + w1) + (w2 + w3)) + ((w4 + w5) + (w6 + w7));
                acc = fmaf(w0, f0, acc);
                acc = fmaf(w1, f1, acc);
                acc = fmaf(w2, f2, acc);
                acc = fmaf(w3, f3, acc);
                acc = fmaf(w4, f4, acc);
                acc = fmaf(w5, f5, acc);
                acc = fmaf(w6, f6, acc);
                acc = fmaf(w7, f7, acc);
            }
        }
        float v = (s > 0.f) ? acc / s : 0.f;
        v = fmaxf(v + bl, 0.f);
        vbuf[wave][lane] = v;
        const float4* vv = (const float4*)vbuf[wave];
        float f = 0.f;
#pragma unroll
        for (int kk = 0; kk < 16; kk++) {
            float4 v4 = vv[kk];                 // LDS broadcast (same addr all lanes)
            float4 w4 = w1v[(kk << 6) + lane];  // contiguous b128, conflict-free
            f = fmaf(v4.x, w4.x, f);
            f = fmaf(v4.y, w4.y, f);
            f = fmaf(v4.z, w4.z, f);
            f = fmaf(v4.w, w4.w, f);
        }
        featB[(size_t)n * 64 + lane] = (_Float16)f;
        float vl = f * al1v, vr = f * ar1v;
#pragma unroll
        for (int m = 1; m < 32; m <<= 1) {
            vl += __shfl_xor(vl, m, 64);
            vr += __shfl_xor(vr, m, 64);
        }
        if ((lane & 31) == 0) {
            ((float*)el2B)[n * 2 + h] = vl;
            ((float*)er2B)[n * 2 + h] = vr;
        }
    }
}

// ---------------- agg1 (layer 1), PAIRED: each wave owns nodes (2g, 2g+1) ----
// Two independent gather chains per wave -> 16 outstanding VMEM instead of 8.
// Joint chunk count; the shorter node's staged slots hold (sv=0,w=0) so its
// extra groups contribute exact zeros -> per-node arithmetic order unchanged.
__global__ __launch_bounds__(256) void aggregate32(
    const int2* __restrict__ rowse, const int* __restrict__ csrc,
    const float2* __restrict__ el2, const float2* __restrict__ er2,
    const _Float16* __restrict__ feat16, const float* __restrict__ b,
    _Float16* __restrict__ ahi, _Float16* __restrict__ alo, int N) {
    __shared__ int2 stA0[4][64], stB0[4][64], stA1[4][64], stB1[4][64];
    int wave = threadIdx.x >> 6, lane = threadIdx.x & 63, h = lane >> 5;
    int g = rfl(blockIdx.x * 4 + wave);
    int n0 = 2 * g, n1 = n0 + 1;
    if (n0 >= N) return;
    bool has1 = (n1 < N);
    float bl = b[lane];
    int2 se0 = rowse[n0];
    int2 se1 = has1 ? rowse[n1] : make_int2(0, 0);
    int beg0 = rfl(se0.x), len0 = rfl(se0.y) - beg0;
    int beg1 = rfl(se1.x), len1 = rfl(se1.y) - beg1;
    float2 rr0 = er2[n0];
    float2 rr1 = has1 ? er2[n1] : make_float2(0.f, 0.f);
    const int2* stH0 = h ? stB0[wave] : stA0[wave];
    const int2* stH1 = h ? stB1[wave] : stA1[wave];
    float s0 = 0.f, acc0 = 0.f, s1 = 0.f, acc1 = 0.f;
    int chunks = max(len0, len1);
    for (int off = 0; off < chunks; off += 64) {
        {
            int sv = 0; float wxv = 0.f, wyv = 0.f;
            if (off + lane < len0) {
                sv = csrc[beg0 + off + lane];
                float2 l = el2[sv];
                float t0 = l.x + rr0.x; t0 = t0 > 0.f ? t0 : NEG_SLOPE * t0;
                float t1 = l.y + rr0.y; t1 = t1 > 0.f ? t1 : NEG_SLOPE * t1;
                wxv = __expf(t0); wyv = __expf(t1);
            }
            stA0[wave][lane] = make_int2(sv, __float_as_int(wxv));
            stB0[wave][lane] = make_int2(sv, __float_as_int(wyv));
        }
        {
            int sv = 0; float wxv = 0.f, wyv = 0.f;
            if (off + lane < len1) {
                sv = csrc[beg1 + off + lane];
                float2 l = el2[sv];
                float t0 = l.x + rr1.x; t0 = t0 > 0.f ? t0 : NEG_SLOPE * t0;
                float t1 = l.y + rr1.y; t1 = t1 > 0.f ? t1 : NEG_SLOPE * t1;
                wxv = __expf(t0); wyv = __expf(t1);
            }
            stA1[wave][lane] = make_int2(sv, __float_as_int(wxv));
            stB1[wave][lane] = make_int2(sv, __float_as_int(wyv));
        }
        int cnt = (min(64, chunks - off) + 7) & ~7;
        for (int j = 0; j < cnt; j += 8) {
            int4 e01 = *(const int4*)(stH0 + j);
            int4 e23 = *(const int4*)(stH0 + j + 2);
            int4 e45 = *(const int4*)(stH0 + j + 4);
            int4 e67 = *(const int4*)(stH0 + j + 6);
            int4 g01 = *(const int4*)(stH1 + j);
            int4 g23 = *(const int4*)(stH1 + j + 2);
            int4 g45 = *(const int4*)(stH1 + j + 4);
            int4 g67 = *(const int4*)(stH1 + j + 6);
            float f0 = (float)feat16[(size_t)e01.x * 64 + lane];
            float f1 = (float)feat16[(size_t)e01.z * 64 + lane];
            float f2 = (float)feat16[(size_t)e23.x * 64 + lane];
            float f3 = (float)feat16[(size_t)e23.z * 64 + lane];
            float f4 = (float)feat16[(size_t)e45.x * 64 + lane];
            float f5 = (float)feat16[(size_t)e45.z * 64 + lane];
            float f6 = (float)feat16[(size_t)e67.x * 64 + lane];
            float f7 = (float)feat16[(size_t)e67.z * 64 + lane];
            float p0 = (float)feat16[(size_t)g01.x * 64 + lane];
            float p1 = (float)feat16[(size_t)g01.z * 64 + lane];
            float p2 = (float)feat16[(size_t)g23.x * 64 + lane];
            float p3 = (float)feat16[(size_t)g23.z * 64 + lane];
            float p4 = (float)feat16[(size_t)g45.x * 64 + lane];
            float p5 = (float)feat16[(size_t)g45.z * 64 + lane];
            float p6 = (float)feat16[(size_t)g67.x * 64 + lane];
            float p7 = (float)feat16[(size_t)g67.z * 64 + lane];
            float w0 = __int_as_float(e01.y), w1 = __int_as_float(e01.w);
            float w2 = __int_as_float(e23.y), w3 = __int_as_float(e23.w);
            float w4 = __int_as_float(e45.y), w5 = __int_as_float(e45.w);
            float w6 = __int_as_float(e67.y), w7 = __int_as_float(e67.w);
            float x0 = __int_as_float(g01.y), x1 = __int_as_float(g01.w);
            float x2 = __int_as_float(g23.y), x3 = __int_as_float(g23.w);
            float x4 = __int_as_float(g45.y), x5 = __int_as_float(g45.w);
            float x6 = __int_as_float(g67.y), x7 = __int_as_float(g67.w);
            s0 += ((w0 + w1) + (w2 + w3)) + ((w4 + w5) + (w6 + w7));
            acc0 = fmaf(w0, f0, acc0);
            acc0 = fmaf(w1, f1, acc0);
            acc0 = fmaf(w2, f2, acc0);
            acc0 = fmaf(w3, f3, acc0);
            acc0 = fmaf(w4, f4, acc0);
            acc0 = fmaf(w5, f5, acc0);
            acc0 = fmaf(w6, f6, acc0);
            acc0 = fmaf(w7, f7, acc0);
            s1 += ((x0 + x1) + (x2 + x3)) + ((x4 + x5) + (x6 + x7));
            acc1 = fmaf(x0, p0, acc1);
            acc1 = fmaf(x1, p1, acc1);
            acc1 = fmaf(x2, p2, acc1);
            acc1 = fmaf(x3, p3, acc1);
            acc1 = fmaf(x4, p4, acc1);
            acc1 = fmaf(x5, p5, acc1);
            acc1 = fmaf(x6, p6, acc1);
            acc1 = fmaf(x7, p7, acc1);
        }
    }
    float v = (s0 > 0.f) ? acc0 / s0 : 0.f;
    v = fmaxf(v + bl, 0.f);
    _Float16 hv = (_Float16)v;
    ahi[(size_t)n0 * 64 + lane] = hv;
    alo[(size_t)n0 * 64 + lane] = (_Float16)(v - (float)hv);
    if (has1) {
        float u = (s1 > 0.f) ? acc1 / s1 : 0.f;
        u = fmaxf(u + bl, 0.f);
        _Float16 hu = (_Float16)u;
        ahi[(size_t)n1 * 64 + lane] = hu;
        alo[(size_t)n1 * 64 + lane] = (_Float16)(u - (float)hu);
    }
}

// ---------------- gemm2: MFMA 64->128, half2-interleaved feat + layer-2 logits ----
__global__ __launch_bounds__(256) void gemm_mfma2(
    const _Float16* __restrict__ Ahi, const _Float16* __restrict__ Alo,
    const _Float16* __restrict__ Wp,
    const float* __restrict__ AL, const float* __restrict__ AR,
    __half2* __restrict__ feat2, float2* __restrict__ el2, float2* __restrict__ er2,
    int N) {
    constexpr int KC = 2, NT = 8;
    int wave = threadIdx.x >> 6, lane = threadIdx.x & 63;
    int mtile = blockIdx.x * 4 + wave;
    if (mtile * 16 >= N) return;
    int m0 = mtile * 16;
    int c = lane & 15, q = lane >> 4;
    v4f acc[NT];
#pragma unroll
    for (int t = 0; t < NT; t++) acc[t] = (v4f){0.f, 0.f, 0.f, 0.f};
    const size_t arow = (size_t)(m0 + c) * 64 + q * 8;
#pragma unroll
    for (int kc = 0; kc < KC; kc++) {
        half8 ah = *(const half8*)(Ahi + arow + kc * 32);
        half8 av = *(const half8*)(Alo + arow + kc * 32);
#pragma unroll
        for (int t = 0; t < NT; t++) {
            half8 b = *(const half8*)(Wp + ((size_t)(t * KC + kc) * 64 + lane) * 8);
            acc[t] = __builtin_amdgcn_mfma_f32_16x16x32_f16(ah, b, acc[t], 0, 0, 0);
            acc[t] = __builtin_amdgcn_mfma_f32_16x16x32_f16(av, b, acc[t], 0, 0, 0);
        }
    }
#pragma unroll
    for (int t = 0; t < NT / 2; t++)
#pragma unroll
        for (int r = 0; r < 4; r++) {
            int row = m0 + q * 4 + r;
            feat2[(size_t)row * 64 + t * 16 + c] =
                __floats2half2_rn(acc[t][r], acc[t + NT / 2][r]);
        }
    float alv[NT], arv[NT];
#pragma unroll
    for (int t = 0; t < NT; t++) { alv[t] = AL[t * 16 + c]; arv[t] = AR[t * 16 + c]; }
#pragma unroll
    for (int r = 0; r < 4; r++) {
        float l0 = 0.f, l1 = 0.f, r0 = 0.f, r1 = 0.f;
#pragma unroll
        for (int t = 0; t < NT; t++) {
            float v = acc[t][r];
            if (t < NT / 2) { l0 = fmaf(v, alv[t], l0); r0 = fmaf(v, arv[t], r0); }
            else            { l1 = fmaf(v, alv[t], l1); r1 = fmaf(v, arv[t], r1); }
        }
#pragma unroll
        for (int m = 1; m < 16; m <<= 1) {
            l0 += __shfl_xor(l0, m, 64);
            l1 += __shfl_xor(l1, m, 64);
            r0 += __shfl_xor(r0, m, 64);
            r1 += __shfl_xor(r1, m, 64);
        }
        if (c == 0) {
            int row = m0 + q * 4 + r;
            el2[row] = make_float2(l0, l1);
            er2[row] = make_float2(r0, r1);
        }
    }
}

// ---------------- agg2 PAIRED: both heads via half2; mean over heads ----------------
__global__ __launch_bounds__(256) void aggregate64_mean(
    const int2* __restrict__ rowse, const int* __restrict__ csrc,
    const float2* __restrict__ el2, const float2* __restrict__ er2,
    const __half2* __restrict__ feat2, const float* __restrict__ b,
    float* __restrict__ out, int N) {
    __shared__ int4 st0[4][64], st1[4][64];
    int wave = threadIdx.x >> 6, lane = threadIdx.x & 63;
    int g = rfl(blockIdx.x * 4 + wave);
    int n0 = 2 * g, n1 = n0 + 1;
    if (n0 >= N) return;
    bool has1 = (n1 < N);
    float b0v = b[lane], b1v = b[64 + lane];
    int2 se0 = rowse[n0];
    int2 se1 = has1 ? rowse[n1] : make_int2(0, 0);
    int beg0 = rfl(se0.x), len0 = rfl(se0.y) - beg0;
    int beg1 = rfl(se1.x), len1 = rfl(se1.y) - beg1;
    float2 rr0 = er2[n0];
    float2 rr1 = has1 ? er2[n1] : make_float2(0.f, 0.f);
    float s00 = 0.f, s01 = 0.f, a00 = 0.f, a01 = 0.f;
    float s10 = 0.f, s11 = 0.f, a10 = 0.f, a11 = 0.f;
    int chunks = max(len0, len1);
    for (int off = 0; off < chunks; off += 64) {
        {
            int sv = 0; float wxv = 0.f, wyv = 0.f;
            if (off + lane < len0) {
                sv = csrc[beg0 + off + lane];
                float2 l = el2[sv];
                float t0 = l.x + rr0.x; t0 = t0 > 0.f ? t0 : NEG_SLOPE * t0;
                float t1 = l.y + rr0.y; t1 = t1 > 0.f ? t1 : NEG_SLOPE * t1;
                wxv = __expf(t0); wyv = __expf(t1);
            }
            st0[wave][lane] = make_int4(sv, __float_as_int(wxv), __float_as_int(wyv), 0);
        }
        {
            int sv = 0; float wxv = 0.f, wyv = 0.f;
            if (off + lane < len1) {
                sv = csrc[beg1 + off + lane];
                float2 l = el2[sv];
                float t0 = l.x + rr1.x; t0 = t0 > 0.f ? t0 : NEG_SLOPE * t0;
                float t1 = l.y + rr1.y; t1 = t1 > 0.f ? t1 : NEG_SLOPE * t1;
                wxv = __expf(t0); wyv = __expf(t1);
            }
            st1[wave][lane] = make_int4(sv, __float_as_int(wxv), __float_as_int(wyv), 0);
        }
        int cnt = (min(64, chunks - off) + 7) & ~7;
        for (int j = 0; j < cnt; j += 8) {
            float2 fv0[8], fv1[8];
            float wx0[8], wy0[8], wx1[8], wy1[8];
#pragma unroll
            for (int u = 0; u < 8; u++) {
                int4 e = st0[wave][j + u];
                wx0[u] = __int_as_float(e.y);
                wy0[u] = __int_as_float(e.z);
                fv0[u] = __half22float2(feat2[(size_t)e.x * 64 + lane]);
            }
#pragma unroll
            for (int u = 0; u < 8; u++) {
                int4 e = st1[wave][j + u];
                wx1[u] = __int_as_float(e.y);
                wy1[u] = __int_as_float(e.z);
                fv1[u] = __half22float2(feat2[(size_t)e.x * 64 + lane]);
            }
#pragma unroll
            for (int u = 0; u < 8; u++) {
                s00 += wx0[u]; s01 += wy0[u];
                a00 = fmaf(wx0[u], fv0[u].x, a00);
                a01 = fmaf(wy0[u], fv0[u].y, a01);
            }
#pragma unroll
            for (int u = 0; u < 8; u++) {
                s10 += wx1[u]; s11 += wy1[u];
                a10 = fmaf(wx1[u], fv1[u].x, a10);
                a11 = fmaf(wy1[u], fv1[u].y, a11);
            }
        }
    }
    float v0 = (s00 > 0.f) ? a00 / s00 : 0.f;
    float v1 = (s01 > 0.f) ? a01 / s01 : 0.f;
    out[(size_t)n0 * 64 + lane] = 0.5f * ((v0 + b0v) + (v1 + b1v));
    if (has1) {
        float u0 = (s10 > 0.f) ? a10 / s10 : 0.f;
        float u1 = (s11 > 0.f) ? a11 / s11 : 0.f;
        out[(size_t)n1 * 64 + lane] = 0.5f * ((u0 + b0v) + (u1 + b1v));
    }
}

// ---------------- launcher ----------------

extern "C" void kernel_launch(void* const* d_in, const int* in_sizes, int n_in,
                              void* d_out, int out_size, void* d_ws, size_t ws_size,
                              hipStream_t stream) {
    const float* x   = (const float*)d_in[0];
    const int*   src = (const int*)d_in[1];
    const int*   dst = (const int*)d_in[2];
    const float* W0  = (const float*)d_in[3];
    const float* al0 = (const float*)d_in[4];
    const float* ar0 = (const float*)d_in[5];
    const float* b0  = (const float*)d_in[6];
    const float* W1  = (const float*)d_in[7];
    const float* al1 = (const float*)d_in[8];
    const float* ar1 = (const float*)d_in[9];
    const float* b1  = (const float*)d_in[10];
    const float* W2  = (const float*)d_in[11];
    const float* al2 = (const float*)d_in[12];
    const float* ar2 = (const float*)d_in[13];
    const float* b2  = (const float*)d_in[14];
    float* out = (float*)d_out;

    const int N = NNODES;
    const int E = in_sizes[1];

    char* p = (char*)d_ws;
    auto alloc = [&](size_t bytes) {
        void* r = (void*)p;
        p += (bytes + 255) & ~(size_t)255;
        return r;
    };
    int*    bcursor = (int*)alloc((size_t)NBKT * 16 * 4);
    int2*   rowse   = (int2*)alloc((size_t)N * 8);
    int2*   ebuf    = (int2*)alloc(((size_t)NBKT * STRIDE + 4096) * 8);
    int*    csrc    = (int*)alloc(((size_t)NBKT * STRIDE + 4096) * 4);
    float2* el2A    = (float2*)alloc((size_t)N * 8);
    float2* er2A    = (float2*)alloc((size_t)N * 8);
    float2* el2B    = (float2*)alloc((size_t)N * 8);
    float2* er2B    = (float2*)alloc((size_t)N * 8);
    _Float16* ahi   = (_Float16*)alloc((size_t)N * 64 * 2);
    _Float16* alo   = (_Float16*)alloc((size_t)N * 64 * 2);
    void*   featA   = alloc((size_t)N * 64 * 4);
    _Float16* featB = (_Float16*)alloc((size_t)N * 64 * 2);
    _Float16* Wp2   = (_Float16*)alloc(8 * 2 * 64 * 8 * 2);

    // 0) zero bucket counters (partition counts from zero)
    hipMemsetAsync(bcursor, 0, (size_t)NBKT * 16 * 4, stream);
    // 1) gemm0 + Wp2 pack + partition, one launch (independent jobs overlap)
    int nch = (E + PCHUNK - 1) / PCHUNK;
    kernelAB<<<786 + nch, 256, 0, stream>>>(x, W0, al0, ar0, (_Float16*)featA, el2A, er2A,
                                            W2, Wp2, src, dst, bcursor, ebuf, E, N);
    // 2) local sort -> rowse + csrc (1024 threads/bucket)
    local_sort<<<NBKT, 1024, 0, stream>>>(ebuf, bcursor, rowse, csrc, N);

    // 3) layer-0 aggregate + fused fp32 gemm1 + layer-1 logits (8-wide, 4096 blocks)
    agg0_gemm1<<<4096, 256, 0, stream>>>(rowse, csrc, el2A, er2A, (const _Float16*)featA,
                                         b0, W1, al1, ar1, featB, el2B, er2B, N);
    // 4) layer-1 aggregate (PAIRED: 2 nodes/wave) -> hi/lo fp16
    int npair = (N + 1) / 2;
    int nbp = (npair + 3) / 4;
    aggregate32<<<nbp, 256, 0, stream>>>(rowse, csrc, el2B, er2B, featB, b1, ahi, alo, N);
    // 5) gemm2 MFMA (64->128)
    int gb = (N / 16 + 3) / 4;
    gemm_mfma2<<<gb, 256, 0, stream>>>(ahi, alo, Wp2, al2, ar2, (__half2*)featA, el2A, er2A, N);
    // 6) layer-2 aggregate (PAIRED), mean over heads
    aggregate64_mean<<<nbp, 256, 0, stream>>>(rowse, csrc, el2A, er2A, (const __half2*)featA,
                                              b2, out, N);
}

// Round 5
// 224.994 us; speedup vs baseline: 1.1778x; 1.0049x over previous
//
#include <hip/hip_runtime.h>
#include <hip/hip_bf16.h>
#include <hip/hip_fp16.h>

#define NNODES 50000
#define NEG_SLOPE 0.2f
#define BKT_SHIFT 8
#define NBKT ((NNODES + 255) >> 8)   // 196 buckets of 256 dsts
#define STRIDE 5120                   // fixed slots per bucket (avg 4082, +16 sigma)
#define PCHUNK 2048                   // partition chunk (256 thr x 8 edges)
#define PEPT 8

typedef _Float16 half8 __attribute__((ext_vector_type(8)));
typedef float v4f __attribute__((ext_vector_type(4)));

__device__ __forceinline__ int rfl(int v) { return __builtin_amdgcn_readfirstlane(v); }

// pack W[K][C] fp32 into MFMA B-fragment order
__device__ __forceinline__ void pack_one(const float* W, _Float16* Wp, int K, int C, int tid) {
    int KC = K / 32;
    int l = tid & 63;
    int kc = (tid >> 6) % KC;
    int t = tid / (KC * 64);
    int cc = l & 15, q = l >> 4;
    half8 b;
#pragma unroll
    for (int j = 0; j < 8; j++)
        b[j] = (_Float16)W[(size_t)(kc * 32 + q * 8 + j) * C + t * 16 + cc];
    *(half8*)(Wp + (size_t)tid * 8) = b;
}

// ---------------- Kernel AB: gemm0 + Wp2 pack + edge partition, ONE launch ----------
__global__ __launch_bounds__(256) void kernelAB(
    const float* __restrict__ x, const float* __restrict__ W0,
    const float* __restrict__ AL, const float* __restrict__ AR,
    _Float16* __restrict__ featA, float2* __restrict__ el2A, float2* __restrict__ er2A,
    const float* __restrict__ W2, _Float16* __restrict__ Wp2,
    const int* __restrict__ src, const int* __restrict__ dst,
    int* __restrict__ bcursor, int2* __restrict__ ebuf, int E, int N) {
    int blk = blockIdx.x;
    if (blk >= 786) {
        // ---- partition branch ----
        __shared__ int hist[NBKT];
        __shared__ int gbase[NBKT];
        int t = threadIdx.x;
        for (int i = t; i < NBKT; i += 256) hist[i] = 0;
        __syncthreads();
        int base = (blk - 786) * PCHUNK;
        int sreg[PEPT], dreg[PEPT], rreg[PEPT], breg[PEPT];
#pragma unroll
        for (int k = 0; k < PEPT; k++) {
            int i = base + k * 256 + t;
            if (i < E) {
                sreg[k] = src[i];
                dreg[k] = dst[i];
                breg[k] = dreg[k] >> BKT_SHIFT;
                rreg[k] = atomicAdd(&hist[breg[k]], 1);
            } else {
                breg[k] = -1;
            }
        }
        __syncthreads();
        for (int i = t; i < NBKT; i += 256)
            if (hist[i]) gbase[i] = i * STRIDE + atomicAdd(&bcursor[i * 16], hist[i]);
        __syncthreads();
#pragma unroll
        for (int k = 0; k < PEPT; k++) {
            if (breg[k] >= 0)
                ebuf[(size_t)(gbase[breg[k]] + rreg[k])] = make_int2(sreg[k], dreg[k]);
        }
        return;
    }
    if (blk >= 782) {
        int tid = (blk - 782) * 256 + threadIdx.x;
        if (tid < 8 * 2 * 64) pack_one(W2, Wp2, 64, 128, tid);
        return;
    }
    // ---- gemm0 branch ----
    int wave = threadIdx.x >> 6, lane = threadIdx.x & 63;
    int mtile = blk * 4 + wave;
    if (mtile * 16 >= N) return;
    int m0 = mtile * 16;
    int c = lane & 15, q = lane >> 4;
    v4f acc[4];
#pragma unroll
    for (int t = 0; t < 4; t++) acc[t] = (v4f){0.f, 0.f, 0.f, 0.f};
    const size_t arow = (size_t)(m0 + c) * 128 + q * 8;
#pragma unroll
    for (int kc = 0; kc < 4; kc++) {
        const float* xr = x + arow + kc * 32;
        float4 f0 = *(const float4*)xr;
        float4 f1 = *(const float4*)(xr + 4);
        float fv[8] = {f0.x, f0.y, f0.z, f0.w, f1.x, f1.y, f1.z, f1.w};
        half8 ah, av;
#pragma unroll
        for (int j = 0; j < 8; j++) {
            ah[j] = (_Float16)fv[j];
            av[j] = (_Float16)(fv[j] - (float)ah[j]);
        }
#pragma unroll
        for (int tt = 0; tt < 4; tt++) {
            half8 b;
#pragma unroll
            for (int j = 0; j < 8; j++)
                b[j] = (_Float16)W0[(size_t)(kc * 32 + q * 8 + j) * 64 + tt * 16 + c];
            acc[tt] = __builtin_amdgcn_mfma_f32_16x16x32_f16(ah, b, acc[tt], 0, 0, 0);
            acc[tt] = __builtin_amdgcn_mfma_f32_16x16x32_f16(av, b, acc[tt], 0, 0, 0);
        }
    }
#pragma unroll
    for (int tt = 0; tt < 4; tt++)
#pragma unroll
        for (int r = 0; r < 4; r++) {
            int row = m0 + q * 4 + r;
            featA[(size_t)row * 64 + tt * 16 + c] = (_Float16)acc[tt][r];
        }
    float alv[4], arv[4];
#pragma unroll
    for (int tt = 0; tt < 4; tt++) { alv[tt] = AL[tt * 16 + c]; arv[tt] = AR[tt * 16 + c]; }
#pragma unroll
    for (int r = 0; r < 4; r++) {
        float l0 = 0.f, l1 = 0.f, r0 = 0.f, r1 = 0.f;
#pragma unroll
        for (int tt = 0; tt < 4; tt++) {
            float v = acc[tt][r];
            if (tt < 2) { l0 = fmaf(v, alv[tt], l0); r0 = fmaf(v, arv[tt], r0); }
            else        { l1 = fmaf(v, alv[tt], l1); r1 = fmaf(v, arv[tt], r1); }
        }
#pragma unroll
        for (int m = 1; m < 16; m <<= 1) {
            l0 += __shfl_xor(l0, m, 64);
            l1 += __shfl_xor(l1, m, 64);
            r0 += __shfl_xor(r0, m, 64);
            r1 += __shfl_xor(r1, m, 64);
        }
        if (c == 0) {
            int row = m0 + q * 4 + r;
            el2A[row] = make_float2(l0, l1);
            er2A[row] = make_float2(r0, r1);
        }
    }
}

// ---------------- local sort: 1024 threads/bucket ----
__global__ __launch_bounds__(1024) void local_sort(const int2* __restrict__ ebuf,
                                                   const int* __restrict__ bcursor,
                                                   int2* __restrict__ rowse,
                                                   int* __restrict__ csrc, int N) {
    __shared__ int lcnt[256], lrow[256], ws[4];
    int b = blockIdx.x;
    int d0 = b << BKT_SHIFT;
    int t = threadIdx.x;
    int base = b * STRIDE;
    int endE = base + bcursor[b * 16];
    if (t < 256) lcnt[t] = 0;
    __syncthreads();
    for (int i = base + t; i < endE; i += 1024)
        atomicAdd(&lcnt[ebuf[i].y - d0], 1);
    __syncthreads();
    int v = (t < 256) ? lcnt[t] : 0;
    int lane = t & 63;
    int x = v;
#pragma unroll
    for (int m = 1; m < 64; m <<= 1) {
        int y = __shfl_up(x, m, 64);
        if (lane >= m) x += y;
    }
    if (t < 256 && lane == 63) ws[t >> 6] = x;
    __syncthreads();
    if (t < 256) {
        int w = t >> 6, waveoff = 0;
#pragma unroll
        for (int k = 0; k < 4; k++) if (k < w) waveoff += ws[k];
        int excl = base + waveoff + x - v;
        lrow[t] = excl;
        int d = d0 + t;
        if (d < N) rowse[d] = make_int2(excl, excl + v);
        lcnt[t] = 0;
    }
    __syncthreads();
    for (int i = base + t; i < endE; i += 1024) {
        int2 e = ebuf[i];
        int ld = e.y - d0;
        int p = lrow[ld] + atomicAdd(&lcnt[ld], 1);
        csrc[p] = e.x;
    }
}

// ---------------- agg0 + fused fp32 matvec gemm1 (64->64) + layer-1 logits ----
// SPLIT staging: stS (indices) written right after the csrc load, stX/stY
// (weights) written after el2-gather+exp. Feat gathers depend only on stS,
// so they issue ~500cy earlier; weights join at the FMA. Bit-identical math.
__global__ __launch_bounds__(256) void agg0_gemm1(
    const int2* __restrict__ rowse, const int* __restrict__ csrc,
    const float2* __restrict__ el2A, const float2* __restrict__ er2A,
    const _Float16* __restrict__ featA, const float* __restrict__ b0,
    const float* __restrict__ W1, const float* __restrict__ al1, const float* __restrict__ ar1,
    _Float16* __restrict__ featB, float2* __restrict__ el2B, float2* __restrict__ er2B,
    int N) {
    __shared__ __attribute__((aligned(16))) int   stS[4][64];
    __shared__ __attribute__((aligned(16))) float stX[4][64], stY[4][64];
    __shared__ float vbuf[4][64];
    __shared__ float4 w1v[16 * 64];   // [k4][lane] -> (W1[4k4+0..3][lane])
    int wave = threadIdx.x >> 6, lane = threadIdx.x & 63, h = lane >> 5;
    for (int i = threadIdx.x; i < 64 * 64; i += 256) {
        int k = i >> 6, cc = i & 63;
        ((float*)w1v)[((((k >> 2) << 6) + cc) << 2) | (k & 3)] = W1[i];
    }
    __syncthreads();
    float bl = b0[lane];
    float al1v = al1[lane], ar1v = ar1[lane];
    const int*   stSw = stS[wave];
    const float* stWH = h ? stY[wave] : stX[wave];
    for (int n0 = blockIdx.x * 4 + wave; n0 < N; n0 += gridDim.x * 4) {
        int n = rfl(n0);
        int2 se = rowse[n];
        int beg = rfl(se.x), end = rfl(se.y);
        float2 rr = er2A[n];
        float s = 0.f, acc = 0.f;
        for (int base = beg; base < end; base += 64) {
            int idx = base + lane;
            bool act = idx < end;
            int sv = act ? csrc[idx] : 0;
            stS[wave][lane] = sv;                      // early: depends only on csrc
            float wxv = 0.f, wyv = 0.f;
            if (act) {
                float2 l = el2A[sv];
                float t0 = l.x + rr.x; t0 = t0 > 0.f ? t0 : NEG_SLOPE * t0;
                float t1 = l.y + rr.y; t1 = t1 > 0.f ? t1 : NEG_SLOPE * t1;
                wxv = __expf(t0); wyv = __expf(t1);
            }
            stX[wave][lane] = wxv;                     // late: joins at FMA
            stY[wave][lane] = wyv;
            int cnt = (min(64, end - base) + 7) & ~7;  // padded: no scalar tail
            for (int j = 0; j < cnt; j += 8) {
                int4 sA = *(const int4*)(stSw + j);
                int4 sB = *(const int4*)(stSw + j + 4);
                float f0 = (float)featA[(size_t)sA.x * 64 + lane];
                float f1 = (float)featA[(size_t)sA.y * 64 + lane];
                float f2 = (float)featA[(size_t)sA.z * 64 + lane];
                float f3 = (float)featA[(size_t)sA.w * 64 + lane];
                float f4 = (float)featA[(size_t)sB.x * 64 + lane];
                float f5 = (float)featA[(size_t)sB.y * 64 + lane];
                float f6 = (float)featA[(size_t)sB.z * 64 + lane];
                float f7 = (float)featA[(size_t)sB.w * 64 + lane];
                float4 wv0 = *(const float4*)(stWH + j);
                float4 wv1 = *(const float4*)(stWH + j + 4);
                s += ((wv0.x + wv0.y) + (wv0.z + wv0.w)) + ((wv1.x + wv1.y) + (wv1.z + wv1.w));
                acc = fmaf(wv0.x, f0, acc);
                acc = fmaf(wv0.y, f1, acc);
                acc = fmaf(wv0.z, f2, acc);
                acc = fmaf(wv0.w, f3, acc);
                acc = fmaf(wv1.x, f4, acc);
                acc = fmaf(wv1.y, f5, acc);
                acc = fmaf(wv1.z, f6, acc);
                acc = fmaf(wv1.w, f7, acc);
            }
        }
        float v = (s > 0.f) ? acc / s : 0.f;
        v = fmaxf(v + bl, 0.f);
        vbuf[wave][lane] = v;
        const float4* vv = (const float4*)vbuf[wave];
        float f = 0.f;
#pragma unroll
        for (int kk = 0; kk < 16; kk++) {
            float4 v4 = vv[kk];                 // LDS broadcast (same addr all lanes)
            float4 w4 = w1v[(kk << 6) + lane];  // contiguous b128, conflict-free
            f = fmaf(v4.x, w4.x, f);
            f = fmaf(v4.y, w4.y, f);
            f = fmaf(v4.z, w4.z, f);
            f = fmaf(v4.w, w4.w, f);
        }
        featB[(size_t)n * 64 + lane] = (_Float16)f;
        float vl = f * al1v, vr = f * ar1v;
#pragma unroll
        for (int m = 1; m < 32; m <<= 1) {
            vl += __shfl_xor(vl, m, 64);
            vr += __shfl_xor(vr, m, 64);
        }
        if ((lane & 31) == 0) {
            ((float*)el2B)[n * 2 + h] = vl;
            ((float*)er2B)[n * 2 + h] = vr;
        }
    }
}

// ---------------- agg1 (layer 1), PAIRED + split staging ----
__global__ __launch_bounds__(256) void aggregate32(
    const int2* __restrict__ rowse, const int* __restrict__ csrc,
    const float2* __restrict__ el2, const float2* __restrict__ er2,
    const _Float16* __restrict__ feat16, const float* __restrict__ b,
    _Float16* __restrict__ ahi, _Float16* __restrict__ alo, int N) {
    __shared__ __attribute__((aligned(16))) int   stS0[4][64], stS1[4][64];
    __shared__ __attribute__((aligned(16))) float stX0[4][64], stY0[4][64];
    __shared__ __attribute__((aligned(16))) float stX1[4][64], stY1[4][64];
    int wave = threadIdx.x >> 6, lane = threadIdx.x & 63, h = lane >> 5;
    int g = rfl(blockIdx.x * 4 + wave);
    int n0 = 2 * g, n1 = n0 + 1;
    if (n0 >= N) return;
    bool has1 = (n1 < N);
    float bl = b[lane];
    int2 se0 = rowse[n0];
    int2 se1 = has1 ? rowse[n1] : make_int2(0, 0);
    int beg0 = rfl(se0.x), len0 = rfl(se0.y) - beg0;
    int beg1 = rfl(se1.x), len1 = rfl(se1.y) - beg1;
    float2 rr0 = er2[n0];
    float2 rr1 = has1 ? er2[n1] : make_float2(0.f, 0.f);
    const int*   stSw0 = stS0[wave];
    const int*   stSw1 = stS1[wave];
    const float* stWH0 = h ? stY0[wave] : stX0[wave];
    const float* stWH1 = h ? stY1[wave] : stX1[wave];
    float s0 = 0.f, acc0 = 0.f, s1 = 0.f, acc1 = 0.f;
    int chunks = max(len0, len1);
    for (int off = 0; off < chunks; off += 64) {
        bool a0 = off + lane < len0;
        bool a1 = off + lane < len1;
        int sv0 = a0 ? csrc[beg0 + off + lane] : 0;
        int sv1 = a1 ? csrc[beg1 + off + lane] : 0;
        stS0[wave][lane] = sv0;                  // early stores: index-only
        stS1[wave][lane] = sv1;
        float wx0 = 0.f, wy0 = 0.f, wx1 = 0.f, wy1 = 0.f;
        if (a0) {
            float2 l = el2[sv0];
            float t0 = l.x + rr0.x; t0 = t0 > 0.f ? t0 : NEG_SLOPE * t0;
            float t1 = l.y + rr0.y; t1 = t1 > 0.f ? t1 : NEG_SLOPE * t1;
            wx0 = __expf(t0); wy0 = __expf(t1);
        }
        if (a1) {
            float2 l = el2[sv1];
            float t0 = l.x + rr1.x; t0 = t0 > 0.f ? t0 : NEG_SLOPE * t0;
            float t1 = l.y + rr1.y; t1 = t1 > 0.f ? t1 : NEG_SLOPE * t1;
            wx1 = __expf(t0); wy1 = __expf(t1);
        }
        stX0[wave][lane] = wx0; stY0[wave][lane] = wy0;
        stX1[wave][lane] = wx1; stY1[wave][lane] = wy1;
        int cnt = (min(64, chunks - off) + 7) & ~7;
        for (int j = 0; j < cnt; j += 8) {
            int4 sA = *(const int4*)(stSw0 + j);
            int4 sB = *(const int4*)(stSw0 + j + 4);
            int4 tA = *(const int4*)(stSw1 + j);
            int4 tB = *(const int4*)(stSw1 + j + 4);
            float f0 = (float)feat16[(size_t)sA.x * 64 + lane];
            float f1 = (float)feat16[(size_t)sA.y * 64 + lane];
            float f2 = (float)feat16[(size_t)sA.z * 64 + lane];
            float f3 = (float)feat16[(size_t)sA.w * 64 + lane];
            float f4 = (float)feat16[(size_t)sB.x * 64 + lane];
            float f5 = (float)feat16[(size_t)sB.y * 64 + lane];
            float f6 = (float)feat16[(size_t)sB.z * 64 + lane];
            float f7 = (float)feat16[(size_t)sB.w * 64 + lane];
            float p0 = (float)feat16[(size_t)tA.x * 64 + lane];
            float p1 = (float)feat16[(size_t)tA.y * 64 + lane];
            float p2 = (float)feat16[(size_t)tA.z * 64 + lane];
            float p3 = (float)feat16[(size_t)tA.w * 64 + lane];
            float p4 = (float)feat16[(size_t)tB.x * 64 + lane];
            float p5 = (float)feat16[(size_t)tB.y * 64 + lane];
            float p6 = (float)feat16[(size_t)tB.z * 64 + lane];
            float p7 = (float)feat16[(size_t)tB.w * 64 + lane];
            float4 wv0 = *(const float4*)(stWH0 + j);
            float4 wv1 = *(const float4*)(stWH0 + j + 4);
            float4 xv0 = *(const float4*)(stWH1 + j);
            float4 xv1 = *(const float4*)(stWH1 + j + 4);
            s0 += ((wv0.x + wv0.y) + (wv0.z + wv0.w)) + ((wv1.x + wv1.y) + (wv1.z + wv1.w));
            acc0 = fmaf(wv0.x, f0, acc0);
            acc0 = fmaf(wv0.y, f1, acc0);
            acc0 = fmaf(wv0.z, f2, acc0);
            acc0 = fmaf(wv0.w, f3, acc0);
            acc0 = fmaf(wv1.x, f4, acc0);
            acc0 = fmaf(wv1.y, f5, acc0);
            acc0 = fmaf(wv1.z, f6, acc0);
            acc0 = fmaf(wv1.w, f7, acc0);
            s1 += ((xv0.x + xv0.y) + (xv0.z + xv0.w)) + ((xv1.x + xv1.y) + (xv1.z + xv1.w));
            acc1 = fmaf(xv0.x, p0, acc1);
            acc1 = fmaf(xv0.y, p1, acc1);
            acc1 = fmaf(xv0.z, p2, acc1);
            acc1 = fmaf(xv0.w, p3, acc1);
            acc1 = fmaf(xv1.x, p4, acc1);
            acc1 = fmaf(xv1.y, p5, acc1);
            acc1 = fmaf(xv1.z, p6, acc1);
            acc1 = fmaf(xv1.w, p7, acc1);
        }
    }
    float v = (s0 > 0.f) ? acc0 / s0 : 0.f;
    v = fmaxf(v + bl, 0.f);
    _Float16 hv = (_Float16)v;
    ahi[(size_t)n0 * 64 + lane] = hv;
    alo[(size_t)n0 * 64 + lane] = (_Float16)(v - (float)hv);
    if (has1) {
        float u = (s1 > 0.f) ? acc1 / s1 : 0.f;
        u = fmaxf(u + bl, 0.f);
        _Float16 hu = (_Float16)u;
        ahi[(size_t)n1 * 64 + lane] = hu;
        alo[(size_t)n1 * 64 + lane] = (_Float16)(u - (float)hu);
    }
}

// ---------------- gemm2: MFMA 64->128, half2-interleaved feat + layer-2 logits ----
__global__ __launch_bounds__(256) void gemm_mfma2(
    const _Float16* __restrict__ Ahi, const _Float16* __restrict__ Alo,
    const _Float16* __restrict__ Wp,
    const float* __restrict__ AL, const float* __restrict__ AR,
    __half2* __restrict__ feat2, float2* __restrict__ el2, float2* __restrict__ er2,
    int N) {
    constexpr int KC = 2, NT = 8;
    int wave = threadIdx.x >> 6, lane = threadIdx.x & 63;
    int mtile = blockIdx.x * 4 + wave;
    if (mtile * 16 >= N) return;
    int m0 = mtile * 16;
    int c = lane & 15, q = lane >> 4;
    v4f acc[NT];
#pragma unroll
    for (int t = 0; t < NT; t++) acc[t] = (v4f){0.f, 0.f, 0.f, 0.f};
    const size_t arow = (size_t)(m0 + c) * 64 + q * 8;
#pragma unroll
    for (int kc = 0; kc < KC; kc++) {
        half8 ah = *(const half8*)(Ahi + arow + kc * 32);
        half8 av = *(const half8*)(Alo + arow + kc * 32);
#pragma unroll
        for (int t = 0; t < NT; t++) {
            half8 b = *(const half8*)(Wp + ((size_t)(t * KC + kc) * 64 + lane) * 8);
            acc[t] = __builtin_amdgcn_mfma_f32_16x16x32_f16(ah, b, acc[t], 0, 0, 0);
            acc[t] = __builtin_amdgcn_mfma_f32_16x16x32_f16(av, b, acc[t], 0, 0, 0);
        }
    }
#pragma unroll
    for (int t = 0; t < NT / 2; t++)
#pragma unroll
        for (int r = 0; r < 4; r++) {
            int row = m0 + q * 4 + r;
            feat2[(size_t)row * 64 + t * 16 + c] =
                __floats2half2_rn(acc[t][r], acc[t + NT / 2][r]);
        }
    float alv[NT], arv[NT];
#pragma unroll
    for (int t = 0; t < NT; t++) { alv[t] = AL[t * 16 + c]; arv[t] = AR[t * 16 + c]; }
#pragma unroll
    for (int r = 0; r < 4; r++) {
        float l0 = 0.f, l1 = 0.f, r0 = 0.f, r1 = 0.f;
#pragma unroll
        for (int t = 0; t < NT; t++) {
            float v = acc[t][r];
            if (t < NT / 2) { l0 = fmaf(v, alv[t], l0); r0 = fmaf(v, arv[t], r0); }
            else            { l1 = fmaf(v, alv[t], l1); r1 = fmaf(v, arv[t], r1); }
        }
#pragma unroll
        for (int m = 1; m < 16; m <<= 1) {
            l0 += __shfl_xor(l0, m, 64);
            l1 += __shfl_xor(l1, m, 64);
            r0 += __shfl_xor(r0, m, 64);
            r1 += __shfl_xor(r1, m, 64);
        }
        if (c == 0) {
            int row = m0 + q * 4 + r;
            el2[row] = make_float2(l0, l1);
            er2[row] = make_float2(r0, r1);
        }
    }
}

// ---------------- agg2 PAIRED + split staging; mean over heads ----------------
__global__ __launch_bounds__(256) void aggregate64_mean(
    const int2* __restrict__ rowse, const int* __restrict__ csrc,
    const float2* __restrict__ el2, const float2* __restrict__ er2,
    const __half2* __restrict__ feat2, const float* __restrict__ b,
    float* __restrict__ out, int N) {
    __shared__ __attribute__((aligned(16))) int   stS0[4][64], stS1[4][64];
    __shared__ __attribute__((aligned(16))) float stX0[4][64], stY0[4][64];
    __shared__ __attribute__((aligned(16))) float stX1[4][64], stY1[4][64];
    int wave = threadIdx.x >> 6, lane = threadIdx.x & 63;
    int g = rfl(blockIdx.x * 4 + wave);
    int n0 = 2 * g, n1 = n0 + 1;
    if (n0 >= N) return;
    bool has1 = (n1 < N);
    float b0v = b[lane], b1v = b[64 + lane];
    int2 se0 = rowse[n0];
    int2 se1 = has1 ? rowse[n1] : make_int2(0, 0);
    int beg0 = rfl(se0.x), len0 = rfl(se0.y) - beg0;
    int beg1 = rfl(se1.x), len1 = rfl(se1.y) - beg1;
    float2 rr0 = er2[n0];
    float2 rr1 = has1 ? er2[n1] : make_float2(0.f, 0.f);
    const int* stSw0 = stS0[wave];
    const int* stSw1 = stS1[wave];
    float s00 = 0.f, s01 = 0.f, a00 = 0.f, a01 = 0.f;
    float s10 = 0.f, s11 = 0.f, a10 = 0.f, a11 = 0.f;
    int chunks = max(len0, len1);
    for (int off = 0; off < chunks; off += 64) {
        bool a0 = off + lane < len0;
        bool a1 = off + lane < len1;
        int sv0 = a0 ? csrc[beg0 + off + lane] : 0;
        int sv1 = a1 ? csrc[beg1 + off + lane] : 0;
        stS0[wave][lane] = sv0;
        stS1[wave][lane] = sv1;
        float wx0 = 0.f, wy0 = 0.f, wx1 = 0.f, wy1 = 0.f;
        if (a0) {
            float2 l = el2[sv0];
            float t0 = l.x + rr0.x; t0 = t0 > 0.f ? t0 : NEG_SLOPE * t0;
            float t1 = l.y + rr0.y; t1 = t1 > 0.f ? t1 : NEG_SLOPE * t1;
            wx0 = __expf(t0); wy0 = __expf(t1);
        }
        if (a1) {
            float2 l = el2[sv1];
            float t0 = l.x + rr1.x; t0 = t0 > 0.f ? t0 : NEG_SLOPE * t0;
            float t1 = l.y + rr1.y; t1 = t1 > 0.f ? t1 : NEG_SLOPE * t1;
            wx1 = __expf(t0); wy1 = __expf(t1);
        }
        stX0[wave][lane] = wx0; stY0[wave][lane] = wy0;
        stX1[wave][lane] = wx1; stY1[wave][lane] = wy1;
        int cnt = (min(64, chunks - off) + 7) & ~7;
        for (int j = 0; j < cnt; j += 8) {
            int4 sA = *(const int4*)(stSw0 + j);
            int4 sB = *(const int4*)(stSw0 + j + 4);
            int4 tA = *(const int4*)(stSw1 + j);
            int4 tB = *(const int4*)(stSw1 + j + 4);
            float2 fv0[8], fv1[8];
            fv0[0] = __half22float2(feat2[(size_t)sA.x * 64 + lane]);
            fv0[1] = __half22float2(feat2[(size_t)sA.y * 64 + lane]);
            fv0[2] = __half22float2(feat2[(size_t)sA.z * 64 + lane]);
            fv0[3] = __half22float2(feat2[(size_t)sA.w * 64 + lane]);
            fv0[4] = __half22float2(feat2[(size_t)sB.x * 64 + lane]);
            fv0[5] = __half22float2(feat2[(size_t)sB.y * 64 + lane]);
            fv0[6] = __half22float2(feat2[(size_t)sB.z * 64 + lane]);
            fv0[7] = __half22float2(feat2[(size_t)sB.w * 64 + lane]);
            fv1[0] = __half22float2(feat2[(size_t)tA.x * 64 + lane]);
            fv1[1] = __half22float2(feat2[(size_t)tA.y * 64 + lane]);
            fv1[2] = __half22float2(feat2[(size_t)tA.z * 64 + lane]);
            fv1[3] = __half22float2(feat2[(size_t)tA.w * 64 + lane]);
            fv1[4] = __half22float2(feat2[(size_t)tB.x * 64 + lane]);
            fv1[5] = __half22float2(feat2[(size_t)tB.y * 64 + lane]);
            fv1[6] = __half22float2(feat2[(size_t)tB.z * 64 + lane]);
            fv1[7] = __half22float2(feat2[(size_t)tB.w * 64 + lane]);
            float4 wx0v = *(const float4*)(stX0[wave] + j);
            float4 wx0w = *(const float4*)(stX0[wave] + j + 4);
            float4 wy0v = *(const float4*)(stY0[wave] + j);
            float4 wy0w = *(const float4*)(stY0[wave] + j + 4);
            float4 wx1v = *(const float4*)(stX1[wave] + j);
            float4 wx1w = *(const float4*)(stX1[wave] + j + 4);
            float4 wy1v = *(const float4*)(stY1[wave] + j);
            float4 wy1w = *(const float4*)(stY1[wave] + j + 4);
            float wxs0[8] = {wx0v.x, wx0v.y, wx0v.z, wx0v.w, wx0w.x, wx0w.y, wx0w.z, wx0w.w};
            float wys0[8] = {wy0v.x, wy0v.y, wy0v.z, wy0v.w, wy0w.x, wy0w.y, wy0w.z, wy0w.w};
            float wxs1[8] = {wx1v.x, wx1v.y, wx1v.z, wx1v.w, wx1w.x, wx1w.y, wx1w.z, wx1w.w};
            float wys1[8] = {wy1v.x, wy1v.y, wy1v.z, wy1v.w, wy1w.x, wy1w.y, wy1w.z, wy1w.w};
#pragma unroll
            for (int u = 0; u < 8; u++) {
                s00 += wxs0[u]; s01 += wys0[u];
                a00 = fmaf(wxs0[u], fv0[u].x, a00);
                a01 = fmaf(wys0[u], fv0[u].y, a01);
            }
#pragma unroll
            for (int u = 0; u < 8; u++) {
                s10 += wxs1[u]; s11 += wys1[u];
                a10 = fmaf(wxs1[u], fv1[u].x, a10);
                a11 = fmaf(wys1[u], fv1[u].y, a11);
            }
        }
    }
    float v0 = (s00 > 0.f) ? a00 / s00 : 0.f;
    float v1 = (s01 > 0.f) ? a01 / s01 : 0.f;
    out[(size_t)n0 * 64 + lane] = 0.5f * ((v0 + b0v) + (v1 + b1v));
    if (has1) {
        float u0 = (s10 > 0.f) ? a10 / s10 : 0.f;
        float u1 = (s11 > 0.f) ? a11 / s11 : 0.f;
        out[(size_t)n1 * 64 + lane] = 0.5f * ((u0 + b0v) + (u1 + b1v));
    }
}

// ---------------- launcher ----------------

extern "C" void kernel_launch(void* const* d_in, const int* in_sizes, int n_in,
                              void* d_out, int out_size, void* d_ws, size_t ws_size,
                              hipStream_t stream) {
    const float* x   = (const float*)d_in[0];
    const int*   src = (const int*)d_in[1];
    const int*   dst = (const int*)d_in[2];
    const float* W0  = (const float*)d_in[3];
    const float* al0 = (const float*)d_in[4];
    const float* ar0 = (const float*)d_in[5];
    const float* b0  = (const float*)d_in[6];
    const float* W1  = (const float*)d_in[7];
    const float* al1 = (const float*)d_in[8];
    const float* ar1 = (const float*)d_in[9];
    const float* b1  = (const float*)d_in[10];
    const float* W2  = (const float*)d_in[11];
    const float* al2 = (const float*)d_in[12];
    const float* ar2 = (const float*)d_in[13];
    const float* b2  = (const float*)d_in[14];
    float* out = (float*)d_out;

    const int N = NNODES;
    const int E = in_sizes[1];

    char* p = (char*)d_ws;
    auto alloc = [&](size_t bytes) {
        void* r = (void*)p;
        p += (bytes + 255) & ~(size_t)255;
        return r;
    };
    int*    bcursor = (int*)alloc((size_t)NBKT * 16 * 4);
    int2*   rowse   = (int2*)alloc((size_t)N * 8);
    int2*   ebuf    = (int2*)alloc(((size_t)NBKT * STRIDE + 4096) * 8);
    int*    csrc    = (int*)alloc(((size_t)NBKT * STRIDE + 4096) * 4);
    float2* el2A    = (float2*)alloc((size_t)N * 8);
    float2* er2A    = (float2*)alloc((size_t)N * 8);
    float2* el2B    = (float2*)alloc((size_t)N * 8);
    float2* er2B    = (float2*)alloc((size_t)N * 8);
    _Float16* ahi   = (_Float16*)alloc((size_t)N * 64 * 2);
    _Float16* alo   = (_Float16*)alloc((size_t)N * 64 * 2);
    void*   featA   = alloc((size_t)N * 64 * 4);
    _Float16* featB = (_Float16*)alloc((size_t)N * 64 * 2);
    _Float16* Wp2   = (_Float16*)alloc(8 * 2 * 64 * 8 * 2);

    // 0) zero bucket counters (partition counts from zero)
    hipMemsetAsync(bcursor, 0, (size_t)NBKT * 16 * 4, stream);
    // 1) gemm0 + Wp2 pack + partition, one launch (independent jobs overlap)
    int nch = (E + PCHUNK - 1) / PCHUNK;
    kernelAB<<<786 + nch, 256, 0, stream>>>(x, W0, al0, ar0, (_Float16*)featA, el2A, er2A,
                                            W2, Wp2, src, dst, bcursor, ebuf, E, N);
    // 2) local sort -> rowse + csrc (1024 threads/bucket)
    local_sort<<<NBKT, 1024, 0, stream>>>(ebuf, bcursor, rowse, csrc, N);

    // 3) layer-0 aggregate + fused fp32 gemm1 + layer-1 logits (grid 2048: r4's 4096 regressed)
    agg0_gemm1<<<2048, 256, 0, stream>>>(rowse, csrc, el2A, er2A, (const _Float16*)featA,
                                         b0, W1, al1, ar1, featB, el2B, er2B, N);
    // 4) layer-1 aggregate (PAIRED, split-stage) -> hi/lo fp16
    int npair = (N + 1) / 2;
    int nbp = (npair + 3) / 4;
    aggregate32<<<nbp, 256, 0, stream>>>(rowse, csrc, el2B, er2B, featB, b1, ahi, alo, N);
    // 5) gemm2 MFMA (64->128)
    int gb = (N / 16 + 3) / 4;
    gemm_mfma2<<<gb, 256, 0, stream>>>(ahi, alo, Wp2, al2, ar2, (__half2*)featA, el2A, er2A, N);
    // 6) layer-2 aggregate (PAIRED, split-stage), mean over heads
    aggregate64_mean<<<nbp, 256, 0, stream>>>(rowse, csrc, el2A, er2A, (const __half2*)featA,
                                              b2, out, N);
}